// Round 1
// baseline (693.330 us; speedup 1.0000x reference)
//
#include <hip/hip_runtime.h>
#include <math.h>

#define PI_F 3.14159265358979323846f
#define KSTEP 0.21959209425992272f  /* (log2(224)-1)/31 */

static __device__ __forceinline__ float wave_reduce_sum(float v) {
#pragma unroll
  for (int off = 32; off; off >>= 1) v += __shfl_down(v, off);
  return v;
}

// ---------------- Kernel 1: token mean ----------------
// t_mean[b*1024+c] = mean_p x[b,c,p]; one wave per (b,c) row.
__global__ __launch_bounds__(256) void mean_kernel(const float* __restrict__ x,
                                                   float* __restrict__ t_mean) {
  const int w = threadIdx.x >> 6;
  const int l = threadIdx.x & 63;
  const int row = blockIdx.x * 4 + w;  // 0..65535
  const float4 v = *reinterpret_cast<const float4*>(x + (size_t)row * 256 + l * 4);
  float s = (v.x + v.y) + (v.z + v.w);
  s = wave_reduce_sum(s);
  if (l == 0) t_mean[row] = s * (1.0f / 256.0f);
}

// ---------------- Generic small GEMM: C = A * B^T + bias ----------------
// C[m,n] = sum_k A[m,k]*B[n,k] + bias[n].  Tile 32m x 64n, K % 32 == 0.
// Per-z offsets allow batching over heads.
__global__ __launch_bounds__(256) void gemm_atbt(
    const float* __restrict__ A, int lda, int aStrideZ,
    const float* __restrict__ B, int ldb, int bStrideZ,
    const float* __restrict__ bias, int biasStrideZ,
    float* __restrict__ C, int ldc, int cStrideZ, int K) {
  const int nt = blockIdx.x, mt = blockIdx.y, z = blockIdx.z;
  const int tid = threadIdx.x;
  A += (size_t)z * aStrideZ + (size_t)mt * 32 * lda;
  B += (size_t)z * bStrideZ + (size_t)nt * 64 * ldb;
  const float* bi = bias + (size_t)z * biasStrideZ + nt * 64;
  C += (size_t)z * cStrideZ + (size_t)mt * 32 * ldc + nt * 64;

  __shared__ float As[32][34];  // [k][m] (+pad)
  __shared__ float Bs[32][68];  // [k][n] (+pad, keeps 16B align: 68*4=272, 272%16==0)

  const int tm = tid >> 4;  // 0..15 -> m = tm*2
  const int tn = tid & 15;  // 0..15 -> n = tn*4
  float acc0[4] = {0, 0, 0, 0}, acc1[4] = {0, 0, 0, 0};

  for (int k0 = 0; k0 < K; k0 += 32) {
    {
      const int m = tid >> 3, kq = tid & 7;
      float4 v = *reinterpret_cast<const float4*>(A + (size_t)m * lda + k0 + kq * 4);
      As[kq * 4 + 0][m] = v.x; As[kq * 4 + 1][m] = v.y;
      As[kq * 4 + 2][m] = v.z; As[kq * 4 + 3][m] = v.w;
    }
#pragma unroll
    for (int r = 0; r < 2; ++r) {
      const int idx = r * 256 + tid;
      const int n = idx >> 3, kq = idx & 7;
      float4 v = *reinterpret_cast<const float4*>(B + (size_t)n * ldb + k0 + kq * 4);
      Bs[kq * 4 + 0][n] = v.x; Bs[kq * 4 + 1][n] = v.y;
      Bs[kq * 4 + 2][n] = v.z; Bs[kq * 4 + 3][n] = v.w;
    }
    __syncthreads();
#pragma unroll
    for (int k = 0; k < 32; ++k) {
      const float a0 = As[k][tm * 2], a1 = As[k][tm * 2 + 1];
      const float4 bb = *reinterpret_cast<const float4*>(&Bs[k][tn * 4]);
      acc0[0] += a0 * bb.x; acc0[1] += a0 * bb.y; acc0[2] += a0 * bb.z; acc0[3] += a0 * bb.w;
      acc1[0] += a1 * bb.x; acc1[1] += a1 * bb.y; acc1[2] += a1 * bb.z; acc1[3] += a1 * bb.w;
    }
    __syncthreads();
  }
  const float4 bb = *reinterpret_cast<const float4*>(bi + tn * 4);
  float4 o0 = make_float4(acc0[0] + bb.x, acc0[1] + bb.y, acc0[2] + bb.z, acc0[3] + bb.w);
  float4 o1 = make_float4(acc1[0] + bb.x, acc1[1] + bb.y, acc1[2] + bb.z, acc1[3] + bb.w);
  *reinterpret_cast<float4*>(C + (size_t)(tm * 2) * ldc + tn * 4) = o0;
  *reinterpret_cast<float4*>(C + (size_t)(tm * 2 + 1) * ldc + tn * 4) = o1;
}

// ---------------- Kernel 3: fused K-GEMM + RoPE + score dot ----------------
// For block (jt, h, b): compute K[d=0..127][j in 32-token tile] = Wk_h @ x_b + bk,
// then S[b,h,1+pj] = sum_d qtilde(b,h,pj,d) * K[d,pj]  (RoPE rotated onto q0).
__global__ __launch_bounds__(256) void k_scores_kernel(
    const float* __restrict__ x, const float* __restrict__ qkv_w,
    const float* __restrict__ qkv_b, const float* __restrict__ q0k0,
    float* __restrict__ S) {
  const int jt = blockIdx.x;  // 8 tiles of 32 tokens
  const int h = blockIdx.y;   // 8 heads
  const int b = blockIdx.z;   // 64 batches
  const int tid = threadIdx.x;

  __shared__ float As[32][128];  // [c][d]  (Wk chunk, transposed)
  __shared__ float Bs[32][36];   // [c][j]  (x chunk, padded)
  __shared__ float red[32][33];  // score reduction

  const float* Wk = qkv_w + (size_t)(1024 + h * 128) * 1024;
  const float* xb = x + (size_t)b * 1024 * 256 + jt * 32;

  const int td = tid >> 3;  // 0..31 -> d = td*4
  const int tj = tid & 7;   // 0..7  -> j = tj*4

  float acc[4][4] = {};
  for (int c0 = 0; c0 < 1024; c0 += 32) {
#pragma unroll
    for (int r = 0; r < 4; ++r) {
      const int idx = r * 256 + tid;
      const int d = idx >> 3, cq = idx & 7;
      float4 v = *reinterpret_cast<const float4*>(Wk + (size_t)d * 1024 + c0 + cq * 4);
      As[cq * 4 + 0][d] = v.x; As[cq * 4 + 1][d] = v.y;
      As[cq * 4 + 2][d] = v.z; As[cq * 4 + 3][d] = v.w;
    }
    {
      const int cc = tid >> 3, jq = tid & 7;
      float4 v = *reinterpret_cast<const float4*>(xb + (size_t)(c0 + cc) * 256 + jq * 4);
      *reinterpret_cast<float4*>(&Bs[cc][jq * 4]) = v;
    }
    __syncthreads();
#pragma unroll
    for (int c = 0; c < 32; ++c) {
      const float4 a = *reinterpret_cast<const float4*>(&As[c][td * 4]);
      const float4 bv = *reinterpret_cast<const float4*>(&Bs[c][tj * 4]);
      acc[0][0] += a.x * bv.x; acc[0][1] += a.x * bv.y; acc[0][2] += a.x * bv.z; acc[0][3] += a.x * bv.w;
      acc[1][0] += a.y * bv.x; acc[1][1] += a.y * bv.y; acc[1][2] += a.y * bv.z; acc[1][3] += a.y * bv.w;
      acc[2][0] += a.z * bv.x; acc[2][1] += a.z * bv.y; acc[2][2] += a.z * bv.z; acc[2][3] += a.z * bv.w;
      acc[3][0] += a.w * bv.x; acc[3][1] += a.w * bv.y; acc[3][2] += a.w * bv.z; acc[3][3] += a.w * bv.w;
    }
    __syncthreads();
  }

  // Epilogue: add k-bias, rotate q0 by per-position RoPE, dot over this thread's 4 dims.
  const float* q0 = q0k0 + (size_t)b * 2048 + h * 128;
  float qv[4], bk[4];
#pragma unroll
  for (int dd = 0; dd < 4; ++dd) {
    qv[dd] = q0[td * 4 + dd];
    bk[dd] = qkv_b[1024 + h * 128 + td * 4 + dd];
  }
  const int m0 = td * 2, m1 = td * 2 + 1;  // band indices (0..63)
  const float band0 = exp2f((float)(m0 & 31) * KSTEP) * PI_F;
  const float band1 = exp2f((float)(m1 & 31) * KSTEP) * PI_F;

#pragma unroll
  for (int jj = 0; jj < 4; ++jj) {
    const int jl = tj * 4 + jj;
    const int pj = jt * 32 + jl;  // spatial position 0..255
    const float cy = -1.0f + (2.0f / 15.0f) * (float)(pj >> 4);
    const float cx = -1.0f + (2.0f / 15.0f) * (float)(pj & 15);
    float sum;
    {
      const float coord = (m0 < 32) ? cy : cx;
      float sn, cs;
      sincosf(coord * band0, &sn, &cs);
      const float ke = acc[0][jj] + bk[0];
      const float ko = acc[1][jj] + bk[1];
      sum = ke * (qv[0] * cs + qv[1] * sn) + ko * (qv[1] * cs - qv[0] * sn);
    }
    {
      const float coord = (m1 < 32) ? cy : cx;
      float sn, cs;
      sincosf(coord * band1, &sn, &cs);
      const float ke = acc[2][jj] + bk[2];
      const float ko = acc[3][jj] + bk[3];
      sum += ke * (qv[2] * cs + qv[3] * sn) + ko * (qv[3] * cs - qv[2] * sn);
    }
    red[jl][td] = sum;
  }
  __syncthreads();
  if (tid < 32) {
    float s = 0.0f;
#pragma unroll
    for (int t = 0; t < 32; ++t) s += red[tid][t];
    S[(size_t)(b * 8 + h) * 257 + 1 + jt * 32 + tid] = s;
  }
}

// ---------------- Kernel 4: token-0 score + softmax ----------------
__global__ __launch_bounds__(64) void softmax_kernel(const float* __restrict__ q0k0,
                                                     const float* __restrict__ S,
                                                     float* __restrict__ attn) {
  const int bh = blockIdx.x;  // 512
  const int b = bh >> 3, h = bh & 7;
  const int l = threadIdx.x;  // 64
  const float scale = 0.08838834764831845f;  // 128^-0.5
  const float* q0 = q0k0 + (size_t)b * 2048 + h * 128;
  const float* k0 = q0k0 + (size_t)b * 2048 + 1024 + h * 128;
  float p = q0[l] * k0[l] + q0[l + 64] * k0[l + 64];
  p = wave_reduce_sum(p);
  const float s0 = __shfl(p, 0);
  const float* Sb = S + (size_t)bh * 257;
  float v[5];
  float mx = -3.0e38f;
  int cnt = 0;
  for (int j = l; j < 257; j += 64) {
    const float s = ((j == 0) ? s0 : Sb[j]) * scale;
    v[cnt++] = s;
    mx = fmaxf(mx, s);
  }
#pragma unroll
  for (int off = 32; off; off >>= 1) mx = fmaxf(mx, __shfl_xor(mx, off));
  float sum = 0.0f;
  for (int i = 0; i < cnt; ++i) {
    v[i] = expf(v[i] - mx);
    sum += v[i];
  }
#pragma unroll
  for (int off = 32; off; off >>= 1) sum += __shfl_xor(sum, off);
  const float inv = 1.0f / sum;
  int i = 0;
  for (int j = l; j < 257; j += 64) attn[(size_t)bh * 257 + j] = v[i++] * inv;
}

// ---------------- Kernel 5: u[b,h,c] = sum_j attn[b,h,j] * t_j[c] ----------------
// (linear-V trick: V is never materialized)
__global__ __launch_bounds__(256) void u_accum_kernel(const float* __restrict__ x,
                                                      const float* __restrict__ t_mean,
                                                      const float* __restrict__ attn,
                                                      float* __restrict__ u) {
  const int ct = blockIdx.x;  // 16 tiles of 64 channels
  const int b = blockIdx.y;   // 64
  const int tid = threadIdx.x;
  __shared__ float aw[257 * 8];  // [j][h] transposed weights
  __shared__ float red[2048];
  for (int i = tid; i < 257 * 8; i += 256) {
    const int j = i >> 3, h = i & 7;
    aw[i] = attn[(size_t)(b * 8 + h) * 257 + j];
  }
  __syncthreads();
  const int cl = tid >> 2, q = tid & 3;
  const int c = ct * 64 + cl;
  const float* xr = x + ((size_t)b * 1024 + c) * 256 + q * 64;
  float acc[8] = {};
#pragma unroll 4
  for (int p4 = 0; p4 < 64; p4 += 4) {
    const float4 xv = *reinterpret_cast<const float4*>(xr + p4);
    const int pbase = q * 64 + p4 + 1;  // token index = position + 1
    const float xs[4] = {xv.x, xv.y, xv.z, xv.w};
#pragma unroll
    for (int e = 0; e < 4; ++e) {
      const float* w8 = &aw[(pbase + e) * 8];
#pragma unroll
      for (int h = 0; h < 8; ++h) acc[h] += w8[h] * xs[e];
    }
  }
  if (q == 0) {
    const float tm = t_mean[b * 1024 + c];
#pragma unroll
    for (int h = 0; h < 8; ++h) acc[h] += aw[h] * tm;  // j = 0 term
  }
#pragma unroll
  for (int h = 0; h < 8; ++h) red[(cl * 4 + q) * 8 + h] = acc[h];
  __syncthreads();
#pragma unroll
  for (int r = 0; r < 2; ++r) {
    const int o = tid * 2 + r;
    const int cl2 = o >> 3, h = o & 7;
    const float s = red[(cl2 * 4 + 0) * 8 + h] + red[(cl2 * 4 + 1) * 8 + h] +
                    red[(cl2 * 4 + 2) * 8 + h] + red[(cl2 * 4 + 3) * 8 + h];
    u[(size_t)(b * 8 + h) * 1024 + ct * 64 + cl2] = s;
  }
}

// ---------------- host side ----------------
extern "C" void kernel_launch(void* const* d_in, const int* in_sizes, int n_in,
                              void* d_out, int out_size, void* d_ws, size_t ws_size,
                              hipStream_t stream) {
  const float* x = (const float*)d_in[0];       // (64,1024,16,16)
  const float* qkv_w = (const float*)d_in[1];   // (3072,1024)
  const float* qkv_b = (const float*)d_in[2];   // (3072)
  const float* proj_w = (const float*)d_in[3];  // (1024,1024)
  const float* proj_b = (const float*)d_in[4];  // (1024)
  float* out = (float*)d_out;                   // (64,1024)

  float* ws = (float*)d_ws;
  float* t_mean = ws;               // 65536
  float* q0k0 = ws + 65536;         // 131072  [b][0..1023]=q0, [1024..2047]=k0
  float* S = ws + 196608;           // 131584  (b,h,257)
  float* attn = ws + 328192;        // 131584
  float* u = ws + 459776;           // 524288  (b,h,1024)
  float* out0 = ws + 984064;        // 65536   (b,1024)

  // 1. token mean
  mean_kernel<<<16384, 256, 0, stream>>>(x, t_mean);

  // 2. q0/k0 = t_mean @ qkv_w[0:2048].T + qkv_b[0:2048]   (M=64,N=2048,K=1024)
  gemm_atbt<<<dim3(32, 2, 1), 256, 0, stream>>>(t_mean, 1024, 0, qkv_w, 1024, 0,
                                                qkv_b, 0, q0k0, 2048, 0, 1024);

  // 3. fused K-GEMM + RoPE + scores for tokens 1..256
  k_scores_kernel<<<dim3(8, 8, 64), 256, 0, stream>>>(x, qkv_w, qkv_b, q0k0, S);

  // 4. token-0 score + softmax -> attn
  softmax_kernel<<<512, 64, 0, stream>>>(q0k0, S, attn);

  // 5. u = attn^T * t   (reads x once)
  u_accum_kernel<<<dim3(16, 64), 256, 0, stream>>>(x, t_mean, attn, u);

  // 6. out0[b, h*128+r] = Wv_h . u[b,h,:] + bv   (z = head)
  gemm_atbt<<<dim3(2, 2, 8), 256, 0, stream>>>(u, 8192, 1024, qkv_w + (size_t)2048 * 1024,
                                               1024, 128 * 1024, qkv_b + 2048, 128, out0,
                                               1024, 128, 1024);

  // 7. out = out0 @ proj_w.T + proj_b   (M=64,N=1024,K=1024)
  gemm_atbt<<<dim3(16, 2, 1), 256, 0, stream>>>(out0, 1024, 0, proj_w, 1024, 0, proj_b, 0,
                                                out, 1024, 0, 1024);
}

// Round 2
// 191.473 us; speedup vs baseline: 3.6210x; 3.6210x over previous
//
#include <hip/hip_runtime.h>
#include <math.h>

#define PI_F 3.14159265358979323846f
#define KSTEP 0.21959209425992272f /* (log2(224)-1)/31 */

using bf16x8 = __attribute__((ext_vector_type(8))) short;
using f32x4 = __attribute__((ext_vector_type(4))) float;
using u16x8 = __attribute__((ext_vector_type(8))) unsigned short;

static __device__ __forceinline__ float wave_reduce_sum(float v) {
#pragma unroll
  for (int off = 32; off; off >>= 1) v += __shfl_down(v, off);
  return v;
}

static __device__ __forceinline__ unsigned short f2bf(float f) {
  unsigned u = __float_as_uint(f);
  return (unsigned short)((u + 0x7fffu + ((u >> 16) & 1u)) >> 16);
}

static __device__ __forceinline__ void gload_lds16(const void* g, void* l) {
  __builtin_amdgcn_global_load_lds((const __attribute__((address_space(1))) unsigned int*)g,
                                   (__attribute__((address_space(3))) unsigned int*)l, 16, 0, 0);
}

// ---------------- transpose x -> bf16 x_t[b][p][c], plus t_mean ----------------
__global__ __launch_bounds__(256) void transpose_mean_kernel(const float* __restrict__ x,
                                                             unsigned short* __restrict__ xt,
                                                             float* __restrict__ t_mean) {
  const int ct = blockIdx.x;  // 16 tiles of 64 channels
  const int b = blockIdx.y;   // 64
  const int t = threadIdx.x;
  __shared__ float tile[64][33];
  const int cl = t >> 2, pq = (t & 3) * 8;   // read role
  const int pl = t >> 3, cq = (t & 7) * 8;   // write role
  float sum = 0.0f;
  const float* xrow = x + ((size_t)(b * 1024 + ct * 64 + cl) * 256) + pq;
  unsigned short* xtb = xt + (size_t)b * 262144 + ct * 64;
  for (int pt = 0; pt < 8; ++pt) {
    const float4 v0 = *reinterpret_cast<const float4*>(xrow + pt * 32);
    const float4 v1 = *reinterpret_cast<const float4*>(xrow + pt * 32 + 4);
    tile[cl][pq + 0] = v0.x; tile[cl][pq + 1] = v0.y; tile[cl][pq + 2] = v0.z; tile[cl][pq + 3] = v0.w;
    tile[cl][pq + 4] = v1.x; tile[cl][pq + 5] = v1.y; tile[cl][pq + 6] = v1.z; tile[cl][pq + 7] = v1.w;
    sum += (v0.x + v0.y) + (v0.z + v0.w) + (v1.x + v1.y) + (v1.z + v1.w);
    __syncthreads();
    u16x8 o;
#pragma unroll
    for (int e = 0; e < 8; ++e) o[e] = f2bf(tile[cq + e][pl]);
    *reinterpret_cast<u16x8*>(xtb + (size_t)(pt * 32 + pl) * 1024 + cq) = o;
    __syncthreads();
  }
  sum += __shfl_xor(sum, 1);
  sum += __shfl_xor(sum, 2);
  if ((t & 3) == 0) t_mean[b * 1024 + ct * 64 + cl] = sum * (1.0f / 256.0f);
}

// ---------------- qkv_w k-rows (1024..2047) -> bf16 ----------------
__global__ __launch_bounds__(256) void convert_wk_kernel(const float* __restrict__ w,
                                                         unsigned short* __restrict__ o) {
  const int i = (blockIdx.x * 256 + threadIdx.x) * 4;
  const float4 v = *reinterpret_cast<const float4*>(w + 1048576 + i);
  ushort4 r;
  r.x = f2bf(v.x); r.y = f2bf(v.y); r.z = f2bf(v.z); r.w = f2bf(v.w);
  *reinterpret_cast<ushort4*>(o + i) = r;
}

// ---------------- RoPE sin/cos table: sc[m][j] = (sin, cos) ----------------
__global__ __launch_bounds__(256) void sc_table_kernel(float2* __restrict__ sc) {
  const int idx = blockIdx.x * 256 + threadIdx.x;  // 16384
  const int m = idx >> 8, j = idx & 255;
  const float band = exp2f((float)(m & 31) * KSTEP) * PI_F;
  const float coord = (m < 32) ? (-1.0f + (2.0f / 15.0f) * (float)(j >> 4))
                               : (-1.0f + (2.0f / 15.0f) * (float)(j & 15));
  float sn, cs;
  sincosf(coord * band, &sn, &cs);
  sc[idx] = make_float2(sn, cs);
}

// ---------------- Generic small GEMM: C = A * B^T + bias (fp32) ----------------
__global__ __launch_bounds__(256) void gemm_atbt(
    const float* __restrict__ A, int lda, int aStrideZ,
    const float* __restrict__ B, int ldb, int bStrideZ,
    const float* __restrict__ bias, int biasStrideZ,
    float* __restrict__ C, int ldc, int cStrideZ, int K) {
  const int nt = blockIdx.x, mt = blockIdx.y, z = blockIdx.z;
  const int tid = threadIdx.x;
  A += (size_t)z * aStrideZ + (size_t)mt * 32 * lda;
  B += (size_t)z * bStrideZ + (size_t)nt * 64 * ldb;
  const float* bi = bias + (size_t)z * biasStrideZ + nt * 64;
  C += (size_t)z * cStrideZ + (size_t)mt * 32 * ldc + nt * 64;

  __shared__ float As[32][34];
  __shared__ float Bs[32][68];

  const int tm = tid >> 4;
  const int tn = tid & 15;
  float acc0[4] = {0, 0, 0, 0}, acc1[4] = {0, 0, 0, 0};

  for (int k0 = 0; k0 < K; k0 += 32) {
    {
      const int m = tid >> 3, kq = tid & 7;
      float4 v = *reinterpret_cast<const float4*>(A + (size_t)m * lda + k0 + kq * 4);
      As[kq * 4 + 0][m] = v.x; As[kq * 4 + 1][m] = v.y;
      As[kq * 4 + 2][m] = v.z; As[kq * 4 + 3][m] = v.w;
    }
#pragma unroll
    for (int r = 0; r < 2; ++r) {
      const int idx = r * 256 + tid;
      const int n = idx >> 3, kq = idx & 7;
      float4 v = *reinterpret_cast<const float4*>(B + (size_t)n * ldb + k0 + kq * 4);
      Bs[kq * 4 + 0][n] = v.x; Bs[kq * 4 + 1][n] = v.y;
      Bs[kq * 4 + 2][n] = v.z; Bs[kq * 4 + 3][n] = v.w;
    }
    __syncthreads();
#pragma unroll
    for (int k = 0; k < 32; ++k) {
      const float a0 = As[k][tm * 2], a1 = As[k][tm * 2 + 1];
      const float4 bb = *reinterpret_cast<const float4*>(&Bs[k][tn * 4]);
      acc0[0] += a0 * bb.x; acc0[1] += a0 * bb.y; acc0[2] += a0 * bb.z; acc0[3] += a0 * bb.w;
      acc1[0] += a1 * bb.x; acc1[1] += a1 * bb.y; acc1[2] += a1 * bb.z; acc1[3] += a1 * bb.w;
    }
    __syncthreads();
  }
  const float4 bb = *reinterpret_cast<const float4*>(bi + tn * 4);
  float4 o0 = make_float4(acc0[0] + bb.x, acc0[1] + bb.y, acc0[2] + bb.z, acc0[3] + bb.w);
  float4 o1 = make_float4(acc1[0] + bb.x, acc1[1] + bb.y, acc1[2] + bb.z, acc1[3] + bb.w);
  *reinterpret_cast<float4*>(C + (size_t)(tm * 2) * ldc + tn * 4) = o0;
  *reinterpret_cast<float4*>(C + (size_t)(tm * 2 + 1) * ldc + tn * 4) = o1;
}

// ---------------- MFMA K-GEMM + RoPE-dot scores ----------------
// Block (b,h): K[128 d][256 j] = Wk_h @ t_j (bf16 MFMA), epilogue rotates q0 by
// table sin/cos and dots -> S[b,h,1+j]. XCD-bijective decode keeps same-b blocks
// on one XCD (x_t[b] = 512 KB L2-resident, read by 8 head-blocks).
__global__ __launch_bounds__(512) void k_scores_mfma(
    const unsigned short* __restrict__ wk, const unsigned short* __restrict__ xt,
    const float* __restrict__ qkv_b, const float* __restrict__ q0k0,
    const float2* __restrict__ sc, float* __restrict__ S) {
  const int l = blockIdx.x;             // 512
  const int b = (l & 7) + ((l >> 6) << 3);
  const int h = (l >> 3) & 7;
  const int tid = threadIdx.x;
  const int w = tid >> 6, lane = tid & 63;
  const int wm = (w >> 2) * 64, wn = (w & 3) * 64;

  __shared__ __align__(16) char smem[49152];
  char* As = smem;            // [128 d][64 c] bf16, 128 B rows, XOR-swizzled chunks
  char* Bs = smem + 16384;    // [256 j][64 c] bf16

  const int rowA = lane >> 3, ci = lane & 7;
  const unsigned short* wkh = wk + (size_t)h * 128 * 1024;
  const unsigned short* xtb = xt + (size_t)b * 262144;

  f32x4 acc[4][4] = {};

  for (int kt = 0; kt < 16; ++kt) {
    const int c0 = kt * 64;
#pragma unroll
    for (int i = 0; i < 2; ++i) {  // stage A: 16 KB
      const int d = (w * 2 + i) * 8 + rowA;
      gload_lds16(wkh + (size_t)d * 1024 + c0 + ((ci ^ (d & 7)) * 8), As + (w * 2 + i) * 1024);
    }
#pragma unroll
    for (int i = 0; i < 4; ++i) {  // stage B: 32 KB
      const int j = (w * 4 + i) * 8 + rowA;
      gload_lds16(xtb + (size_t)j * 1024 + c0 + ((ci ^ (j & 7)) * 8), Bs + (w * 4 + i) * 1024);
    }
    __syncthreads();
#pragma unroll
    for (int kk = 0; kk < 2; ++kk) {
      const int coff = kk * 64 + (lane >> 4) * 16;
      bf16x8 af[4], bfr[4];
#pragma unroll
      for (int mi = 0; mi < 4; ++mi) {
        const int d = wm + mi * 16 + (lane & 15);
        af[mi] = *reinterpret_cast<const bf16x8*>(As + d * 128 + (coff ^ ((d & 7) << 4)));
      }
#pragma unroll
      for (int ni = 0; ni < 4; ++ni) {
        const int j = wn + ni * 16 + (lane & 15);
        bfr[ni] = *reinterpret_cast<const bf16x8*>(Bs + j * 128 + (coff ^ ((j & 7) << 4)));
      }
#pragma unroll
      for (int mi = 0; mi < 4; ++mi)
#pragma unroll
        for (int ni = 0; ni < 4; ++ni)
          acc[mi][ni] = __builtin_amdgcn_mfma_f32_16x16x32_bf16(af[mi], bfr[ni], acc[mi][ni], 0, 0, 0);
    }
    __syncthreads();
  }

  // Epilogue: S[j] partials = sum over this lane's K rows of cs*P + sn*Q.
  const float* q0 = q0k0 + (size_t)b * 2048 + h * 128;
  const float* bk = qkv_b + 1024 + h * 128;
  const int colj = lane & 15, rgrp = lane >> 4;
  float partial[4] = {0, 0, 0, 0};
#pragma unroll
  for (int mi = 0; mi < 4; ++mi) {
#pragma unroll
    for (int pp = 0; pp < 2; ++pp) {
      const int d0 = wm + mi * 16 + rgrp * 4 + pp * 2;
      const int m = d0 >> 1;
      const float2 qv = *reinterpret_cast<const float2*>(q0 + d0);
      const float2 bv = *reinterpret_cast<const float2*>(bk + d0);
#pragma unroll
      for (int ni = 0; ni < 4; ++ni) {
        const int j = wn + ni * 16 + colj;
        const float ke = acc[mi][ni][pp * 2] + bv.x;
        const float ko = acc[mi][ni][pp * 2 + 1] + bv.y;
        const float2 t = sc[m * 256 + j];
        const float P = ke * qv.x + ko * qv.y;
        const float Q = ke * qv.y - ko * qv.x;
        partial[ni] += t.y * P + t.x * Q;
      }
    }
  }
  __syncthreads();  // done with As/Bs; reuse as reduction buffer
  float* red = reinterpret_cast<float*>(smem);  // [256][9]
#pragma unroll
  for (int ni = 0; ni < 4; ++ni)
    red[(wn + ni * 16 + colj) * 9 + (w >> 2) * 4 + rgrp] = partial[ni];
  __syncthreads();
  if (tid < 256) {
    float s = 0.0f;
#pragma unroll
    for (int k = 0; k < 8; ++k) s += red[tid * 9 + k];
    S[(size_t)(b * 8 + h) * 257 + 1 + tid] = s;
  }
}

// ---------------- token-0 score + softmax ----------------
__global__ __launch_bounds__(64) void softmax_kernel(const float* __restrict__ q0k0,
                                                     const float* __restrict__ S,
                                                     float* __restrict__ attn) {
  const int bh = blockIdx.x;
  const int b = bh >> 3, h = bh & 7;
  const int l = threadIdx.x;
  const float scale = 0.08838834764831845f;
  const float* q0 = q0k0 + (size_t)b * 2048 + h * 128;
  const float* k0 = q0k0 + (size_t)b * 2048 + 1024 + h * 128;
  float p = q0[l] * k0[l] + q0[l + 64] * k0[l + 64];
  p = wave_reduce_sum(p);
  const float s0 = __shfl(p, 0);
  const float* Sb = S + (size_t)bh * 257;
  float v[5];
  float mx = -3.0e38f;
  int cnt = 0;
  for (int j = l; j < 257; j += 64) {
    const float s = ((j == 0) ? s0 : Sb[j]) * scale;
    v[cnt++] = s;
    mx = fmaxf(mx, s);
  }
#pragma unroll
  for (int off = 32; off; off >>= 1) mx = fmaxf(mx, __shfl_xor(mx, off));
  float sum = 0.0f;
  for (int i = 0; i < cnt; ++i) {
    v[i] = expf(v[i] - mx);
    sum += v[i];
  }
#pragma unroll
  for (int off = 32; off; off >>= 1) sum += __shfl_xor(sum, off);
  const float inv = 1.0f / sum;
  int i = 0;
  for (int j = l; j < 257; j += 64) attn[(size_t)bh * 257 + j] = v[i++] * inv;
}

// ---------------- u[b,h,c] = sum_j attn[b,h,j] * t_j[c] ----------------
__global__ __launch_bounds__(256) void u_accum_kernel(const float* __restrict__ x,
                                                      const float* __restrict__ t_mean,
                                                      const float* __restrict__ attn,
                                                      float* __restrict__ u) {
  const int ct = blockIdx.x;
  const int b = blockIdx.y;
  const int tid = threadIdx.x;
  __shared__ float aw[257 * 8];
  __shared__ float red[2048];
  for (int i = tid; i < 257 * 8; i += 256) {
    const int j = i >> 3, h = i & 7;
    aw[i] = attn[(size_t)(b * 8 + h) * 257 + j];
  }
  __syncthreads();
  const int cl = tid >> 2, q = tid & 3;
  const int c = ct * 64 + cl;
  const float* xr = x + ((size_t)b * 1024 + c) * 256 + q * 64;
  float acc[8] = {};
#pragma unroll 4
  for (int p4 = 0; p4 < 64; p4 += 4) {
    const float4 xv = *reinterpret_cast<const float4*>(xr + p4);
    const int pbase = q * 64 + p4 + 1;
    const float xs[4] = {xv.x, xv.y, xv.z, xv.w};
#pragma unroll
    for (int e = 0; e < 4; ++e) {
      const float* w8 = &aw[(pbase + e) * 8];
#pragma unroll
      for (int h = 0; h < 8; ++h) acc[h] += w8[h] * xs[e];
    }
  }
  if (q == 0) {
    const float tm = t_mean[b * 1024 + c];
#pragma unroll
    for (int h = 0; h < 8; ++h) acc[h] += aw[h] * tm;
  }
#pragma unroll
  for (int h = 0; h < 8; ++h) red[(cl * 4 + q) * 8 + h] = acc[h];
  __syncthreads();
#pragma unroll
  for (int r = 0; r < 2; ++r) {
    const int o = tid * 2 + r;
    const int cl2 = o >> 3, h = o & 7;
    const float s = red[(cl2 * 4 + 0) * 8 + h] + red[(cl2 * 4 + 1) * 8 + h] +
                    red[(cl2 * 4 + 2) * 8 + h] + red[(cl2 * 4 + 3) * 8 + h];
    u[(size_t)(b * 8 + h) * 1024 + ct * 64 + cl2] = s;
  }
}

// ---------------- host side ----------------
extern "C" void kernel_launch(void* const* d_in, const int* in_sizes, int n_in,
                              void* d_out, int out_size, void* d_ws, size_t ws_size,
                              hipStream_t stream) {
  const float* x = (const float*)d_in[0];
  const float* qkv_w = (const float*)d_in[1];
  const float* qkv_b = (const float*)d_in[2];
  const float* proj_w = (const float*)d_in[3];
  const float* proj_b = (const float*)d_in[4];
  float* out = (float*)d_out;

  float* ws = (float*)d_ws;
  float* t_mean = ws;                                     // 65536
  float* q0k0 = ws + 65536;                               // 131072
  float* S = ws + 196608;                                 // 131584
  float* attn = ws + 328192;                              // 131584
  float* u = ws + 459776;                                 // 524288
  float* out0 = ws + 984064;                              // 65536
  float2* sc = (float2*)(ws + 1049600);                   // 16384 float2
  unsigned short* wk_bf = (unsigned short*)(ws + 1082368);  // 1 M u16
  unsigned short* x_t = (unsigned short*)(ws + 1606656);    // 16.78 M u16

  transpose_mean_kernel<<<dim3(16, 64), 256, 0, stream>>>(x, x_t, t_mean);
  convert_wk_kernel<<<1024, 256, 0, stream>>>(qkv_w, wk_bf);
  sc_table_kernel<<<64, 256, 0, stream>>>(sc);

  gemm_atbt<<<dim3(32, 2, 1), 256, 0, stream>>>(t_mean, 1024, 0, qkv_w, 1024, 0,
                                                qkv_b, 0, q0k0, 2048, 0, 1024);

  k_scores_mfma<<<512, 512, 0, stream>>>(wk_bf, x_t, qkv_b, q0k0, sc, S);

  softmax_kernel<<<512, 64, 0, stream>>>(q0k0, S, attn);

  u_accum_kernel<<<dim3(16, 64), 256, 0, stream>>>(x, t_mean, attn, u);

  gemm_atbt<<<dim3(2, 2, 8), 256, 0, stream>>>(u, 8192, 1024, qkv_w + (size_t)2048 * 1024,
                                               1024, 128 * 1024, qkv_b + 2048, 128, out0,
                                               1024, 128, 1024);

  gemm_atbt<<<dim3(16, 2, 1), 256, 0, stream>>>(out0, 1024, 0, proj_w, 1024, 0, proj_b, 0,
                                                out, 1024, 0, 1024);
}

// Round 3
// 114.720 us; speedup vs baseline: 6.0437x; 1.6690x over previous
//
#include <hip/hip_runtime.h>
#include <math.h>

#define PI_F 3.14159265358979323846f
#define KSTEP 0.21959209425992272f /* (log2(224)-1)/31 */

using bf16x8 = __attribute__((ext_vector_type(8))) short;
using f32x4 = __attribute__((ext_vector_type(4))) float;
using u16x8 = __attribute__((ext_vector_type(8))) unsigned short;

static __device__ __forceinline__ float wave_reduce_sum(float v) {
#pragma unroll
  for (int off = 32; off; off >>= 1) v += __shfl_down(v, off);
  return v;
}

static __device__ __forceinline__ unsigned short f2bf(float f) {
  unsigned u = __float_as_uint(f);
  return (unsigned short)((u + 0x7fffu + ((u >> 16) & 1u)) >> 16);
}

static __device__ __forceinline__ void gload_lds16(const void* g, void* l) {
  __builtin_amdgcn_global_load_lds((const __attribute__((address_space(1))) unsigned int*)g,
                                   (__attribute__((address_space(3))) unsigned int*)l, 16, 0, 0);
}

// ---------------- fused prep: transpose x->bf16 x_t + t_mean | Wk->bf16 | sc table ----------------
__global__ __launch_bounds__(256) void prep_kernel(const float* __restrict__ x,
                                                   const float* __restrict__ qkv_w,
                                                   unsigned short* __restrict__ xt,
                                                   float* __restrict__ t_mean,
                                                   unsigned short* __restrict__ wk_bf,
                                                   float2* __restrict__ sc) {
  const int bid = blockIdx.x;
  const int t = threadIdx.x;
  __shared__ float tile[64][33];
  if (bid < 1024) {
    const int ct = bid & 15, b = bid >> 4;
    const int cl = t >> 2, pq = (t & 3) * 8;  // read role
    const int pl = t >> 3, cq = (t & 7) * 8;  // write role
    float sum = 0.0f;
    const float* xrow = x + ((size_t)(b * 1024 + ct * 64 + cl) * 256) + pq;
    unsigned short* xtb = xt + (size_t)b * 262144 + ct * 64;
    for (int pt = 0; pt < 8; ++pt) {
      const float4 v0 = *reinterpret_cast<const float4*>(xrow + pt * 32);
      const float4 v1 = *reinterpret_cast<const float4*>(xrow + pt * 32 + 4);
      tile[cl][pq + 0] = v0.x; tile[cl][pq + 1] = v0.y; tile[cl][pq + 2] = v0.z; tile[cl][pq + 3] = v0.w;
      tile[cl][pq + 4] = v1.x; tile[cl][pq + 5] = v1.y; tile[cl][pq + 6] = v1.z; tile[cl][pq + 7] = v1.w;
      sum += (v0.x + v0.y) + (v0.z + v0.w) + (v1.x + v1.y) + (v1.z + v1.w);
      __syncthreads();
      u16x8 o;
#pragma unroll
      for (int e = 0; e < 8; ++e) o[e] = f2bf(tile[cq + e][pl]);
      *reinterpret_cast<u16x8*>(xtb + (size_t)(pt * 32 + pl) * 1024 + cq) = o;
      __syncthreads();
    }
    sum += __shfl_xor(sum, 1);
    sum += __shfl_xor(sum, 2);
    if ((t & 3) == 0) t_mean[b * 1024 + ct * 64 + cl] = sum * (1.0f / 256.0f);
  } else if (bid < 2048) {
    const int i = ((bid - 1024) * 256 + t) * 4;
    const float4 v = *reinterpret_cast<const float4*>(qkv_w + 1048576 + i);
    ushort4 r;
    r.x = f2bf(v.x); r.y = f2bf(v.y); r.z = f2bf(v.z); r.w = f2bf(v.w);
    *reinterpret_cast<ushort4*>(wk_bf + i) = r;
  } else {
    const int idx = (bid - 2048) * 256 + t;  // 16384
    const int m = idx >> 8, j = idx & 255;
    const float band = exp2f((float)(m & 31) * KSTEP) * PI_F;
    const float coord = (m < 32) ? (-1.0f + (2.0f / 15.0f) * (float)(j >> 4))
                                 : (-1.0f + (2.0f / 15.0f) * (float)(j & 15));
    float sn, cs;
    sincosf(coord * band, &sn, &cs);
    sc[idx] = make_float2(sn, cs);
  }
}

// ---------------- split-K skinny GEMM: Cp[kc] = A * B^T (K-chunk = 256) ----------------
// grid: (N/64, M/32, Z*KC); per z: A offset aStrideZ, B offset bStrideZ, C offset cStrideZ.
__global__ __launch_bounds__(256) void gemm_splitk(
    const float* __restrict__ A, int lda, int aStrideZ,
    const float* __restrict__ B, int ldb, int bStrideZ,
    float* __restrict__ Cp, int ldc, int cStrideZ, int cStrideKc, int KC) {
  const int nt = blockIdx.x, mt = blockIdx.y;
  const int z = blockIdx.z / KC, kc = blockIdx.z % KC;
  const int tid = threadIdx.x;
  A += (size_t)z * aStrideZ + (size_t)mt * 32 * lda + kc * 256;
  B += (size_t)z * bStrideZ + (size_t)nt * 64 * ldb + kc * 256;
  Cp += (size_t)kc * cStrideKc + (size_t)z * cStrideZ + (size_t)mt * 32 * ldc + nt * 64;

  __shared__ float As[32][34];
  __shared__ float Bs[32][68];

  const int tm = tid >> 4;
  const int tn = tid & 15;
  float acc0[4] = {0, 0, 0, 0}, acc1[4] = {0, 0, 0, 0};

  for (int k0 = 0; k0 < 256; k0 += 32) {
    {
      const int m = tid >> 3, kq = tid & 7;
      float4 v = *reinterpret_cast<const float4*>(A + (size_t)m * lda + k0 + kq * 4);
      As[kq * 4 + 0][m] = v.x; As[kq * 4 + 1][m] = v.y;
      As[kq * 4 + 2][m] = v.z; As[kq * 4 + 3][m] = v.w;
    }
#pragma unroll
    for (int r = 0; r < 2; ++r) {
      const int idx = r * 256 + tid;
      const int n = idx >> 3, kq = idx & 7;
      float4 v = *reinterpret_cast<const float4*>(B + (size_t)n * ldb + k0 + kq * 4);
      Bs[kq * 4 + 0][n] = v.x; Bs[kq * 4 + 1][n] = v.y;
      Bs[kq * 4 + 2][n] = v.z; Bs[kq * 4 + 3][n] = v.w;
    }
    __syncthreads();
#pragma unroll
    for (int k = 0; k < 32; ++k) {
      const float a0 = As[k][tm * 2], a1 = As[k][tm * 2 + 1];
      const float4 bb = *reinterpret_cast<const float4*>(&Bs[k][tn * 4]);
      acc0[0] += a0 * bb.x; acc0[1] += a0 * bb.y; acc0[2] += a0 * bb.z; acc0[3] += a0 * bb.w;
      acc1[0] += a1 * bb.x; acc1[1] += a1 * bb.y; acc1[2] += a1 * bb.z; acc1[3] += a1 * bb.w;
    }
    __syncthreads();
  }
  *reinterpret_cast<float4*>(Cp + (size_t)(tm * 2) * ldc + tn * 4) =
      make_float4(acc0[0], acc0[1], acc0[2], acc0[3]);
  *reinterpret_cast<float4*>(Cp + (size_t)(tm * 2 + 1) * ldc + tn * 4) =
      make_float4(acc1[0], acc1[1], acc1[2], acc1[3]);
}

// ---------------- reduce 4 split-K partials + bias ----------------
__global__ __launch_bounds__(256) void reduce4_bias(const float* __restrict__ part,
                                                    const float* __restrict__ bias,
                                                    float* __restrict__ out) {
  const int i = blockIdx.x * 256 + threadIdx.x;  // 65536
  out[i] = part[i] + part[i + 65536] + part[i + 131072] + part[i + 196608] + bias[i & 1023];
}

// ---------------- MFMA K-GEMM + RoPE-dot scores ----------------
// Block (b,h): K[128 d][256 j] = Wk_h @ t_j (bf16 MFMA), epilogue reduces q0 from
// split-K partials, rotates by table sin/cos, dots -> S[b,h,1+j].
__global__ __launch_bounds__(512) void k_scores_mfma(
    const unsigned short* __restrict__ wk, const unsigned short* __restrict__ xt,
    const float* __restrict__ qkv_b, const float* __restrict__ q0p,
    const float2* __restrict__ sc, float* __restrict__ S) {
  const int l = blockIdx.x;             // 512
  const int b = (l & 7) + ((l >> 6) << 3);
  const int h = (l >> 3) & 7;
  const int tid = threadIdx.x;
  const int w = tid >> 6, lane = tid & 63;
  const int wm = (w >> 2) * 64, wn = (w & 3) * 64;

  __shared__ __align__(16) char smem[49152];
  char* As = smem;            // [128 d][64 c] bf16, 128 B rows, XOR-swizzled chunks
  char* Bs = smem + 16384;    // [256 j][64 c] bf16

  const int rowA = lane >> 3, ci = lane & 7;
  const unsigned short* wkh = wk + (size_t)h * 128 * 1024;
  const unsigned short* xtb = xt + (size_t)b * 262144;

  f32x4 acc[4][4] = {};

  for (int kt = 0; kt < 16; ++kt) {
    const int c0 = kt * 64;
#pragma unroll
    for (int i = 0; i < 2; ++i) {  // stage A: 16 KB
      const int d = (w * 2 + i) * 8 + rowA;
      gload_lds16(wkh + (size_t)d * 1024 + c0 + ((ci ^ (d & 7)) * 8), As + (w * 2 + i) * 1024);
    }
#pragma unroll
    for (int i = 0; i < 4; ++i) {  // stage B: 32 KB
      const int j = (w * 4 + i) * 8 + rowA;
      gload_lds16(xtb + (size_t)j * 1024 + c0 + ((ci ^ (j & 7)) * 8), Bs + (w * 4 + i) * 1024);
    }
    __syncthreads();
#pragma unroll
    for (int kk = 0; kk < 2; ++kk) {
      const int coff = kk * 64 + (lane >> 4) * 16;
      bf16x8 af[4], bfr[4];
#pragma unroll
      for (int mi = 0; mi < 4; ++mi) {
        const int d = wm + mi * 16 + (lane & 15);
        af[mi] = *reinterpret_cast<const bf16x8*>(As + d * 128 + (coff ^ ((d & 7) << 4)));
      }
#pragma unroll
      for (int ni = 0; ni < 4; ++ni) {
        const int j = wn + ni * 16 + (lane & 15);
        bfr[ni] = *reinterpret_cast<const bf16x8*>(Bs + j * 128 + (coff ^ ((j & 7) << 4)));
      }
#pragma unroll
      for (int mi = 0; mi < 4; ++mi)
#pragma unroll
        for (int ni = 0; ni < 4; ++ni)
          acc[mi][ni] = __builtin_amdgcn_mfma_f32_16x16x32_bf16(af[mi], bfr[ni], acc[mi][ni], 0, 0, 0);
    }
    __syncthreads();
  }

  // Reduce q0 from split-K partials + bias into LDS (region beyond red[]).
  float* q0_lds = reinterpret_cast<float*>(smem + 40960);  // 128 floats
  if (tid < 128) {
    const float* qp = q0p + (size_t)b * 2048 + h * 128 + tid;
    q0_lds[tid] = qkv_b[h * 128 + tid] + qp[0] + qp[131072] + qp[262144] + qp[393216];
  }
  __syncthreads();

  // Epilogue: S[j] partials = sum over this lane's K rows of cs*P + sn*Q.
  const float* bk = qkv_b + 1024 + h * 128;
  const int colj = lane & 15, rgrp = lane >> 4;
  float partial[4] = {0, 0, 0, 0};
#pragma unroll
  for (int mi = 0; mi < 4; ++mi) {
#pragma unroll
    for (int pp = 0; pp < 2; ++pp) {
      const int d0 = wm + mi * 16 + rgrp * 4 + pp * 2;
      const int m = d0 >> 1;
      const float2 qv = *reinterpret_cast<const float2*>(q0_lds + d0);
      const float2 bv = *reinterpret_cast<const float2*>(bk + d0);
#pragma unroll
      for (int ni = 0; ni < 4; ++ni) {
        const int j = wn + ni * 16 + colj;
        const float ke = acc[mi][ni][pp * 2] + bv.x;
        const float ko = acc[mi][ni][pp * 2 + 1] + bv.y;
        const float2 t = sc[m * 256 + j];
        const float P = ke * qv.x + ko * qv.y;
        const float Q = ke * qv.y - ko * qv.x;
        partial[ni] += t.y * P + t.x * Q;
      }
    }
  }
  float* red = reinterpret_cast<float*>(smem);  // [256][9] = 36864 B, below q0_lds
#pragma unroll
  for (int ni = 0; ni < 4; ++ni)
    red[(wn + ni * 16 + colj) * 9 + (w >> 2) * 4 + rgrp] = partial[ni];
  __syncthreads();
  if (tid < 256) {
    float s = 0.0f;
#pragma unroll
    for (int k = 0; k < 8; ++k) s += red[tid * 9 + k];
    S[(size_t)(b * 8 + h) * 257 + 1 + tid] = s;
  }
}

// ---------------- token-0 score + softmax (q0/k0 reduced inline from partials) ----------------
__global__ __launch_bounds__(64) void softmax_kernel(const float* __restrict__ q0p,
                                                     const float* __restrict__ qkv_b,
                                                     const float* __restrict__ S,
                                                     float* __restrict__ attn) {
  const int bh = blockIdx.x;
  const int b = bh >> 3, h = bh & 7;
  const int l = threadIdx.x;
  const float scale = 0.08838834764831845f;
  float q0a = qkv_b[h * 128 + l], q0b = qkv_b[h * 128 + l + 64];
  float k0a = qkv_b[1024 + h * 128 + l], k0b = qkv_b[1024 + h * 128 + l + 64];
  const float* base = q0p + (size_t)b * 2048;
#pragma unroll
  for (int kc = 0; kc < 4; ++kc) {
    const float* pp = base + (size_t)kc * 131072;
    q0a += pp[h * 128 + l];
    q0b += pp[h * 128 + l + 64];
    k0a += pp[1024 + h * 128 + l];
    k0b += pp[1024 + h * 128 + l + 64];
  }
  float p = q0a * k0a + q0b * k0b;
  p = wave_reduce_sum(p);
  const float s0 = __shfl(p, 0);
  const float* Sb = S + (size_t)bh * 257;
  float v[5];
  float mx = -3.0e38f;
  int cnt = 0;
  for (int j = l; j < 257; j += 64) {
    const float s = ((j == 0) ? s0 : Sb[j]) * scale;
    v[cnt++] = s;
    mx = fmaxf(mx, s);
  }
#pragma unroll
  for (int off = 32; off; off >>= 1) mx = fmaxf(mx, __shfl_xor(mx, off));
  float sum = 0.0f;
  for (int i = 0; i < cnt; ++i) {
    v[i] = expf(v[i] - mx);
    sum += v[i];
  }
#pragma unroll
  for (int off = 32; off; off >>= 1) sum += __shfl_xor(sum, off);
  const float inv = 1.0f / sum;
  int i = 0;
  for (int j = l; j < 257; j += 64) attn[(size_t)bh * 257 + j] = v[i++] * inv;
}

// ---------------- u[b,h,c] = sum_j attn[b,h,j] * t_j[c] ----------------
__global__ __launch_bounds__(256) void u_accum_kernel(const float* __restrict__ x,
                                                      const float* __restrict__ t_mean,
                                                      const float* __restrict__ attn,
                                                      float* __restrict__ u) {
  const int ct = blockIdx.x;
  const int b = blockIdx.y;
  const int tid = threadIdx.x;
  __shared__ float aw[257 * 8];
  __shared__ float red[2048];
  for (int i = tid; i < 257 * 8; i += 256) {
    const int j = i >> 3, h = i & 7;
    aw[i] = attn[(size_t)(b * 8 + h) * 257 + j];
  }
  __syncthreads();
  const int cl = tid >> 2, q = tid & 3;
  const int c = ct * 64 + cl;
  const float* xr = x + ((size_t)b * 1024 + c) * 256 + q * 64;
  float acc[8] = {};
#pragma unroll 4
  for (int p4 = 0; p4 < 64; p4 += 4) {
    const float4 xv = *reinterpret_cast<const float4*>(xr + p4);
    const int pbase = q * 64 + p4 + 1;
    const float xs[4] = {xv.x, xv.y, xv.z, xv.w};
#pragma unroll
    for (int e = 0; e < 4; ++e) {
      const float* w8 = &aw[(pbase + e) * 8];
#pragma unroll
      for (int h = 0; h < 8; ++h) acc[h] += w8[h] * xs[e];
    }
  }
  if (q == 0) {
    const float tm = t_mean[b * 1024 + c];
#pragma unroll
    for (int h = 0; h < 8; ++h) acc[h] += aw[h] * tm;
  }
#pragma unroll
  for (int h = 0; h < 8; ++h) red[(cl * 4 + q) * 8 + h] = acc[h];
  __syncthreads();
#pragma unroll
  for (int r = 0; r < 2; ++r) {
    const int o = tid * 2 + r;
    const int cl2 = o >> 3, h = o & 7;
    const float s = red[(cl2 * 4 + 0) * 8 + h] + red[(cl2 * 4 + 1) * 8 + h] +
                    red[(cl2 * 4 + 2) * 8 + h] + red[(cl2 * 4 + 3) * 8 + h];
    u[(size_t)(b * 8 + h) * 1024 + ct * 64 + cl2] = s;
  }
}

// ---------------- host side ----------------
extern "C" void kernel_launch(void* const* d_in, const int* in_sizes, int n_in,
                              void* d_out, int out_size, void* d_ws, size_t ws_size,
                              hipStream_t stream) {
  const float* x = (const float*)d_in[0];
  const float* qkv_w = (const float*)d_in[1];
  const float* qkv_b = (const float*)d_in[2];
  const float* proj_w = (const float*)d_in[3];
  const float* proj_b = (const float*)d_in[4];
  float* out = (float*)d_out;

  float* ws = (float*)d_ws;
  float* t_mean = ws;                                        // 65536
  float* q0k0_part = ws + 65536;                             // 4*64*2048 = 524288
  float* S = ws + 589824;                                    // 131584
  float* attn = ws + 721408;                                 // 131584
  float* u = ws + 852992;                                    // 524288
  float* out0 = ws + 1377280;                                // 65536
  float* out0_part = ws + 1442816;                           // 262144
  float* out_part = ws + 1704960;                            // 262144
  float2* sc = (float2*)(ws + 1967104);                      // 16384 float2
  unsigned short* wk_bf = (unsigned short*)(ws + 1999872);   // 1M u16
  unsigned short* x_t = (unsigned short*)(ws + 2524160);     // 16.78M u16

  // 1. fused prep: transpose+mean (1024 blocks) | wk->bf16 (1024) | sc table (64)
  prep_kernel<<<2112, 256, 0, stream>>>(x, qkv_w, x_t, t_mean, wk_bf, sc);

  // 2. q0k0 partials: t_mean @ qkv_w[0:2048].T  (M=64,N=2048,K=4x256)
  gemm_splitk<<<dim3(32, 2, 4), 256, 0, stream>>>(t_mean, 1024, 0, qkv_w, 1024, 0,
                                                  q0k0_part, 2048, 0, 131072, 4);

  // 3. fused K-GEMM + RoPE + scores (reduces q0 partials inline)
  k_scores_mfma<<<512, 512, 0, stream>>>(wk_bf, x_t, qkv_b, q0k0_part, sc, S);

  // 4. token-0 score + softmax (reduces q0/k0 partials inline)
  softmax_kernel<<<512, 64, 0, stream>>>(q0k0_part, qkv_b, S, attn);

  // 5. u = attn^T * t
  u_accum_kernel<<<dim3(16, 64), 256, 0, stream>>>(x, t_mean, attn, u);

  // 6. out0 partials: per-head Wv_h . u  (Z=8, N=128 each, K=4x256)
  gemm_splitk<<<dim3(2, 2, 32), 256, 0, stream>>>(u, 8192, 1024,
                                                  qkv_w + (size_t)2048 * 1024, 1024, 131072,
                                                  out0_part, 1024, 128, 65536, 4);
  reduce4_bias<<<256, 256, 0, stream>>>(out0_part, qkv_b + 2048, out0);

  // 7. out partials: out0 @ proj_w.T  (M=64,N=1024,K=4x256)
  gemm_splitk<<<dim3(16, 2, 4), 256, 0, stream>>>(out0, 1024, 0, proj_w, 1024, 0,
                                                  out_part, 1024, 0, 65536, 4);
  reduce4_bias<<<256, 256, 0, stream>>>(out_part, proj_b, out);
}

// Round 4
// 114.043 us; speedup vs baseline: 6.0796x; 1.0059x over previous
//
#include <hip/hip_runtime.h>
#include <math.h>

#define PI_F 3.14159265358979323846f
#define KSTEP 0.21959209425992272f /* (log2(224)-1)/31 */

using bf16x8 = __attribute__((ext_vector_type(8))) short;
using f32x4 = __attribute__((ext_vector_type(4))) float;
using u16x8 = __attribute__((ext_vector_type(8))) unsigned short;

static __device__ __forceinline__ float wave_reduce_sum(float v) {
#pragma unroll
  for (int off = 32; off; off >>= 1) v += __shfl_down(v, off);
  return v;
}

static __device__ __forceinline__ unsigned short f2bf(float f) {
  unsigned u = __float_as_uint(f);
  return (unsigned short)((u + 0x7fffu + ((u >> 16) & 1u)) >> 16);
}

static __device__ __forceinline__ float bf2f(unsigned short s) {
  return __uint_as_float(((unsigned)s) << 16);
}

static __device__ __forceinline__ void gload_lds16(const void* g, void* l) {
  __builtin_amdgcn_global_load_lds((const __attribute__((address_space(1))) unsigned int*)g,
                                   (__attribute__((address_space(3))) unsigned int*)l, 16, 0, 0);
}

// ---------------- fused prep: transpose x->bf16 x_t + t_mean | Wk->bf16 | sc table ----------------
__global__ __launch_bounds__(256) void prep_kernel(const float* __restrict__ x,
                                                   const float* __restrict__ qkv_w,
                                                   unsigned short* __restrict__ xt,
                                                   float* __restrict__ t_mean,
                                                   unsigned short* __restrict__ wk_bf,
                                                   float2* __restrict__ sc) {
  const int bid = blockIdx.x;
  const int t = threadIdx.x;
  __shared__ float tile[64][33];
  if (bid < 1024) {
    const int ct = bid & 15, b = bid >> 4;
    const int cl = t >> 2, pq = (t & 3) * 8;  // read role
    const int pl = t >> 3, cq = (t & 7) * 8;  // write role
    float sum = 0.0f;
    const float* xrow = x + ((size_t)(b * 1024 + ct * 64 + cl) * 256) + pq;
    unsigned short* xtb = xt + (size_t)b * 262144 + ct * 64;
    for (int pt = 0; pt < 8; ++pt) {
      const float4 v0 = *reinterpret_cast<const float4*>(xrow + pt * 32);
      const float4 v1 = *reinterpret_cast<const float4*>(xrow + pt * 32 + 4);
      tile[cl][pq + 0] = v0.x; tile[cl][pq + 1] = v0.y; tile[cl][pq + 2] = v0.z; tile[cl][pq + 3] = v0.w;
      tile[cl][pq + 4] = v1.x; tile[cl][pq + 5] = v1.y; tile[cl][pq + 6] = v1.z; tile[cl][pq + 7] = v1.w;
      sum += (v0.x + v0.y) + (v0.z + v0.w) + (v1.x + v1.y) + (v1.z + v1.w);
      __syncthreads();
      u16x8 o;
#pragma unroll
      for (int e = 0; e < 8; ++e) o[e] = f2bf(tile[cq + e][pl]);
      *reinterpret_cast<u16x8*>(xtb + (size_t)(pt * 32 + pl) * 1024 + cq) = o;
      __syncthreads();
    }
    sum += __shfl_xor(sum, 1);
    sum += __shfl_xor(sum, 2);
    if ((t & 3) == 0) t_mean[b * 1024 + ct * 64 + cl] = sum * (1.0f / 256.0f);
  } else if (bid < 2048) {
    const int i = ((bid - 1024) * 256 + t) * 4;
    const float4 v = *reinterpret_cast<const float4*>(qkv_w + 1048576 + i);
    ushort4 r;
    r.x = f2bf(v.x); r.y = f2bf(v.y); r.z = f2bf(v.z); r.w = f2bf(v.w);
    *reinterpret_cast<ushort4*>(wk_bf + i) = r;
  } else {
    const int idx = (bid - 2048) * 256 + t;  // 16384
    const int m = idx >> 8, j = idx & 255;
    const float band = exp2f((float)(m & 31) * KSTEP) * PI_F;
    const float coord = (m < 32) ? (-1.0f + (2.0f / 15.0f) * (float)(j >> 4))
                                 : (-1.0f + (2.0f / 15.0f) * (float)(j & 15));
    float sn, cs;
    sincosf(coord * band, &sn, &cs);
    sc[idx] = make_float2(sn, cs);
  }
}

// ---------------- split-K skinny GEMM: Cp[kc] = A * B^T (K-chunk = 256) ----------------
__global__ __launch_bounds__(256) void gemm_splitk(
    const float* __restrict__ A, int lda, int aStrideZ,
    const float* __restrict__ B, int ldb, int bStrideZ,
    float* __restrict__ Cp, int ldc, int cStrideZ, int cStrideKc, int KC) {
  const int nt = blockIdx.x, mt = blockIdx.y;
  const int z = blockIdx.z / KC, kc = blockIdx.z % KC;
  const int tid = threadIdx.x;
  A += (size_t)z * aStrideZ + (size_t)mt * 32 * lda + kc * 256;
  B += (size_t)z * bStrideZ + (size_t)nt * 64 * ldb + kc * 256;
  Cp += (size_t)kc * cStrideKc + (size_t)z * cStrideZ + (size_t)mt * 32 * ldc + nt * 64;

  __shared__ float As[32][34];
  __shared__ float Bs[32][68];

  const int tm = tid >> 4;
  const int tn = tid & 15;
  float acc0[4] = {0, 0, 0, 0}, acc1[4] = {0, 0, 0, 0};

  for (int k0 = 0; k0 < 256; k0 += 32) {
    {
      const int m = tid >> 3, kq = tid & 7;
      float4 v = *reinterpret_cast<const float4*>(A + (size_t)m * lda + k0 + kq * 4);
      As[kq * 4 + 0][m] = v.x; As[kq * 4 + 1][m] = v.y;
      As[kq * 4 + 2][m] = v.z; As[kq * 4 + 3][m] = v.w;
    }
#pragma unroll
    for (int r = 0; r < 2; ++r) {
      const int idx = r * 256 + tid;
      const int n = idx >> 3, kq = idx & 7;
      float4 v = *reinterpret_cast<const float4*>(B + (size_t)n * ldb + k0 + kq * 4);
      Bs[kq * 4 + 0][n] = v.x; Bs[kq * 4 + 1][n] = v.y;
      Bs[kq * 4 + 2][n] = v.z; Bs[kq * 4 + 3][n] = v.w;
    }
    __syncthreads();
#pragma unroll
    for (int k = 0; k < 32; ++k) {
      const float a0 = As[k][tm * 2], a1 = As[k][tm * 2 + 1];
      const float4 bb = *reinterpret_cast<const float4*>(&Bs[k][tn * 4]);
      acc0[0] += a0 * bb.x; acc0[1] += a0 * bb.y; acc0[2] += a0 * bb.z; acc0[3] += a0 * bb.w;
      acc1[0] += a1 * bb.x; acc1[1] += a1 * bb.y; acc1[2] += a1 * bb.z; acc1[3] += a1 * bb.w;
    }
    __syncthreads();
  }
  *reinterpret_cast<float4*>(Cp + (size_t)(tm * 2) * ldc + tn * 4) =
      make_float4(acc0[0], acc0[1], acc0[2], acc0[3]);
  *reinterpret_cast<float4*>(Cp + (size_t)(tm * 2 + 1) * ldc + tn * 4) =
      make_float4(acc1[0], acc1[1], acc1[2], acc1[3]);
}

// ---------------- proj GEMM with inline 4-partial A reduce + Wv-bias ----------------
// A[m][k] = bias_v[k] + sum_r out0_part[r][m][k]; C partials for final reduce.
__global__ __launch_bounds__(256) void gemm_proj_splitk(
    const float* __restrict__ Apart, const float* __restrict__ abias,
    const float* __restrict__ B, float* __restrict__ Cp) {
  const int nt = blockIdx.x, mt = blockIdx.y, kc = blockIdx.z;
  const int tid = threadIdx.x;
  B += (size_t)nt * 64 * 1024 + kc * 256;
  Cp += (size_t)kc * 65536 + (size_t)mt * 32 * 1024 + nt * 64;

  __shared__ float As[32][34];
  __shared__ float Bs[32][68];

  const int tm = tid >> 4;
  const int tn = tid & 15;
  float acc0[4] = {0, 0, 0, 0}, acc1[4] = {0, 0, 0, 0};

  for (int k0 = 0; k0 < 256; k0 += 32) {
    {
      const int m = tid >> 3, kq = tid & 7;
      const int kg = kc * 256 + k0 + kq * 4;
      const float* Ab = Apart + (size_t)(mt * 32 + m) * 1024 + kg;
      float4 v = *reinterpret_cast<const float4*>(abias + kg);
#pragma unroll
      for (int r = 0; r < 4; ++r) {
        const float4 p = *reinterpret_cast<const float4*>(Ab + (size_t)r * 65536);
        v.x += p.x; v.y += p.y; v.z += p.z; v.w += p.w;
      }
      As[kq * 4 + 0][m] = v.x; As[kq * 4 + 1][m] = v.y;
      As[kq * 4 + 2][m] = v.z; As[kq * 4 + 3][m] = v.w;
    }
#pragma unroll
    for (int r = 0; r < 2; ++r) {
      const int idx = r * 256 + tid;
      const int n = idx >> 3, kq = idx & 7;
      float4 v = *reinterpret_cast<const float4*>(B + (size_t)n * 1024 + k0 + kq * 4);
      Bs[kq * 4 + 0][n] = v.x; Bs[kq * 4 + 1][n] = v.y;
      Bs[kq * 4 + 2][n] = v.z; Bs[kq * 4 + 3][n] = v.w;
    }
    __syncthreads();
#pragma unroll
    for (int k = 0; k < 32; ++k) {
      const float a0 = As[k][tm * 2], a1 = As[k][tm * 2 + 1];
      const float4 bb = *reinterpret_cast<const float4*>(&Bs[k][tn * 4]);
      acc0[0] += a0 * bb.x; acc0[1] += a0 * bb.y; acc0[2] += a0 * bb.z; acc0[3] += a0 * bb.w;
      acc1[0] += a1 * bb.x; acc1[1] += a1 * bb.y; acc1[2] += a1 * bb.z; acc1[3] += a1 * bb.w;
    }
    __syncthreads();
  }
  *reinterpret_cast<float4*>(Cp + (size_t)(tm * 2) * 1024 + tn * 4) =
      make_float4(acc0[0], acc0[1], acc0[2], acc0[3]);
  *reinterpret_cast<float4*>(Cp + (size_t)(tm * 2 + 1) * 1024 + tn * 4) =
      make_float4(acc1[0], acc1[1], acc1[2], acc1[3]);
}

// ---------------- reduce 4 split-K partials + bias ----------------
__global__ __launch_bounds__(256) void reduce4_bias(const float* __restrict__ part,
                                                    const float* __restrict__ bias,
                                                    float* __restrict__ out) {
  const int i = blockIdx.x * 256 + threadIdx.x;  // 65536
  out[i] = part[i] + part[i + 65536] + part[i + 131072] + part[i + 196608] + bias[i & 1023];
}

// ---------------- MFMA K-GEMM + RoPE-dot scores, double-buffered ----------------
// Block (b,h,jt): K[128 d][128 j] = Wk_h @ t_j (bf16 MFMA, LDS dbuf, 1 barrier/iter),
// epilogue reduces q0 from split-K partials, rotates by sc table, dots -> S.
__global__ __launch_bounds__(512) void k_scores_mfma(
    const unsigned short* __restrict__ wk, const unsigned short* __restrict__ xt,
    const float* __restrict__ qkv_b, const float* __restrict__ q0p,
    const float2* __restrict__ sc, float* __restrict__ S) {
  const int l = blockIdx.x;  // 1024; same-b blocks land on one XCD (l&7 preserved)
  const int b = ((l >> 7) << 3) + (l & 7);
  const int h = (l >> 4) & 7;
  const int jt = (l >> 3) & 1;
  const int tid = threadIdx.x;
  const int w = tid >> 6, lane = tid & 63;
  const int wm = (w >> 2) * 64, wn = (w & 3) * 32;

  __shared__ __align__(16) char smem[65536];
  // buf sel*32768: A [128 d][64 c] @ +0 (16 KB), B [128 j][64 c] @ +16384 (16 KB)

  const int rowA = lane >> 3, ci = lane & 7;
  const unsigned short* wkh = wk + (size_t)h * 128 * 1024;
  const unsigned short* xtb = xt + (size_t)b * 262144 + (size_t)jt * 128 * 1024;

  f32x4 acc[4][2] = {};

#define STAGE(sel, c0)                                                                   \
  {                                                                                      \
    char* Ab = smem + (sel)*32768;                                                       \
    char* Bb = Ab + 16384;                                                               \
    _Pragma("unroll") for (int i = 0; i < 2; ++i) {                                      \
      const int r = (w * 2 + i) * 8 + rowA;                                              \
      gload_lds16(wkh + (size_t)r * 1024 + (c0) + ((ci ^ (r & 7)) * 8),                  \
                  Ab + (w * 2 + i) * 1024);                                              \
      gload_lds16(xtb + (size_t)r * 1024 + (c0) + ((ci ^ (r & 7)) * 8),                  \
                  Bb + (w * 2 + i) * 1024);                                              \
    }                                                                                    \
  }

  STAGE(0, 0);
  __syncthreads();
  int cur = 0;
  for (int kt = 0; kt < 16; ++kt) {
    if (kt < 15) STAGE(cur ^ 1, (kt + 1) * 64);
    const char* Ab = smem + cur * 32768;
    const char* Bb = Ab + 16384;
#pragma unroll
    for (int kk = 0; kk < 2; ++kk) {
      const int coff = kk * 64 + (lane >> 4) * 16;
      bf16x8 af[4], bfr[2];
#pragma unroll
      for (int mi = 0; mi < 4; ++mi) {
        const int d = wm + mi * 16 + (lane & 15);
        af[mi] = *reinterpret_cast<const bf16x8*>(Ab + d * 128 + (coff ^ ((d & 7) << 4)));
      }
#pragma unroll
      for (int ni = 0; ni < 2; ++ni) {
        const int j = wn + ni * 16 + (lane & 15);
        bfr[ni] = *reinterpret_cast<const bf16x8*>(Bb + j * 128 + (coff ^ ((j & 7) << 4)));
      }
#pragma unroll
      for (int mi = 0; mi < 4; ++mi)
#pragma unroll
        for (int ni = 0; ni < 2; ++ni)
          acc[mi][ni] = __builtin_amdgcn_mfma_f32_16x16x32_bf16(af[mi], bfr[ni], acc[mi][ni], 0, 0, 0);
    }
    __syncthreads();  // drains this iter's prefetch (vmcnt0) + readers done with buf[cur]
    cur ^= 1;
  }
#undef STAGE

  // Reduce q0 from split-K partials + bias into LDS.
  float* q0_lds = reinterpret_cast<float*>(smem + 57344);  // 128 floats
  if (tid < 128) {
    const float* qp = q0p + (size_t)b * 2048 + h * 128 + tid;
    q0_lds[tid] = qkv_b[h * 128 + tid] + qp[0] + qp[131072] + qp[262144] + qp[393216];
  }
  __syncthreads();

  // Epilogue: per-lane RoPE-rotated dot partials.
  const float* bk = qkv_b + 1024 + h * 128;
  const int colj = lane & 15, rgrp = lane >> 4;
  float partial[2] = {0, 0};
#pragma unroll
  for (int mi = 0; mi < 4; ++mi) {
#pragma unroll
    for (int pp = 0; pp < 2; ++pp) {
      const int d0 = wm + mi * 16 + rgrp * 4 + pp * 2;
      const int m = d0 >> 1;
      const float2 qv = *reinterpret_cast<const float2*>(q0_lds + d0);
      const float2 bv = *reinterpret_cast<const float2*>(bk + d0);
#pragma unroll
      for (int ni = 0; ni < 2; ++ni) {
        const int j = jt * 128 + wn + ni * 16 + colj;
        const float ke = acc[mi][ni][pp * 2] + bv.x;
        const float ko = acc[mi][ni][pp * 2 + 1] + bv.y;
        const float2 t = sc[m * 256 + j];
        const float P = ke * qv.x + ko * qv.y;
        const float Q = ke * qv.y - ko * qv.x;
        partial[ni] += t.y * P + t.x * Q;
      }
    }
  }
  float* red = reinterpret_cast<float*>(smem);  // [128][9] = 4608 B
#pragma unroll
  for (int ni = 0; ni < 2; ++ni)
    red[(wn + ni * 16 + colj) * 9 + (w >> 2) * 4 + rgrp] = partial[ni];
  __syncthreads();
  if (tid < 128) {
    float s = 0.0f;
#pragma unroll
    for (int k = 0; k < 8; ++k) s += red[tid * 9 + k];
    S[(size_t)(b * 8 + h) * 257 + 1 + jt * 128 + tid] = s;
  }
}

// ---------------- token-0 score + softmax (q0/k0 reduced inline from partials) ----------------
__global__ __launch_bounds__(64) void softmax_kernel(const float* __restrict__ q0p,
                                                     const float* __restrict__ qkv_b,
                                                     const float* __restrict__ S,
                                                     float* __restrict__ attn) {
  const int bh = blockIdx.x;
  const int b = bh >> 3, h = bh & 7;
  const int l = threadIdx.x;
  const float scale = 0.08838834764831845f;
  float q0a = qkv_b[h * 128 + l], q0b = qkv_b[h * 128 + l + 64];
  float k0a = qkv_b[1024 + h * 128 + l], k0b = qkv_b[1024 + h * 128 + l + 64];
  const float* base = q0p + (size_t)b * 2048;
#pragma unroll
  for (int kc = 0; kc < 4; ++kc) {
    const float* pp = base + (size_t)kc * 131072;
    q0a += pp[h * 128 + l];
    q0b += pp[h * 128 + l + 64];
    k0a += pp[1024 + h * 128 + l];
    k0b += pp[1024 + h * 128 + l + 64];
  }
  float p = q0a * k0a + q0b * k0b;
  p = wave_reduce_sum(p);
  const float s0 = __shfl(p, 0);
  const float* Sb = S + (size_t)bh * 257;
  float v[5];
  float mx = -3.0e38f;
  int cnt = 0;
  for (int j = l; j < 257; j += 64) {
    const float s = ((j == 0) ? s0 : Sb[j]) * scale;
    v[cnt++] = s;
    mx = fmaxf(mx, s);
  }
#pragma unroll
  for (int off = 32; off; off >>= 1) mx = fmaxf(mx, __shfl_xor(mx, off));
  float sum = 0.0f;
  for (int i = 0; i < cnt; ++i) {
    v[i] = expf(v[i] - mx);
    sum += v[i];
  }
#pragma unroll
  for (int off = 32; off; off >>= 1) sum += __shfl_xor(sum, off);
  const float inv = 1.0f / sum;
  int i = 0;
  for (int j = l; j < 257; j += 64) attn[(size_t)bh * 257 + j] = v[i++] * inv;
}

// ---------------- u[b,h,c] = sum_j attn[b,h,j] * t_j[c]  (reads bf16 x_t) ----------------
__global__ __launch_bounds__(256) void u_accum_kernel(const unsigned short* __restrict__ xt,
                                                      const float* __restrict__ t_mean,
                                                      const float* __restrict__ attn,
                                                      float* __restrict__ u) {
  const int ct = blockIdx.x;  // 8 tiles of 128 channels
  const int b = blockIdx.y;
  const int tid = threadIdx.x;
  __shared__ float aw[2056];
  __shared__ float red[8192];  // [8 q][1024]
  for (int i = tid; i < 2056; i += 256) aw[i] = attn[(size_t)(b * 8 + (i & 7)) * 257 + (i >> 3)];
  __syncthreads();
  const int cl = tid & 31, q = tid >> 5;
  const int c = ct * 128 + cl * 4;
  const unsigned short* xr = xt + (size_t)b * 262144 + c;
  float acc[8][4] = {};
  for (int p = q * 32; p < q * 32 + 32; ++p) {
    const ushort4 v = *reinterpret_cast<const ushort4*>(xr + (size_t)p * 1024);
    const float xs[4] = {bf2f(v.x), bf2f(v.y), bf2f(v.z), bf2f(v.w)};
    const float* w8 = &aw[(p + 1) * 8];
#pragma unroll
    for (int hh = 0; hh < 8; ++hh)
#pragma unroll
      for (int e = 0; e < 4; ++e) acc[hh][e] += w8[hh] * xs[e];
  }
#pragma unroll
  for (int hh = 0; hh < 8; ++hh)
#pragma unroll
    for (int e = 0; e < 4; ++e) red[q * 1024 + (cl * 8 + hh) * 4 + e] = acc[hh][e];
  __syncthreads();
#pragma unroll
  for (int r = 0; r < 4; ++r) {
    const int o = tid * 4 + r;  // 0..1023
    const int cl2 = o >> 5, hh = (o >> 2) & 7, e = o & 3;
    float s = 0.0f;
#pragma unroll
    for (int qq = 0; qq < 8; ++qq) s += red[qq * 1024 + o];
    const int cc = ct * 128 + cl2 * 4 + e;
    s += aw[hh] * t_mean[b * 1024 + cc];
    u[(size_t)(b * 8 + hh) * 1024 + cc] = s;
  }
}

// ---------------- host side ----------------
extern "C" void kernel_launch(void* const* d_in, const int* in_sizes, int n_in,
                              void* d_out, int out_size, void* d_ws, size_t ws_size,
                              hipStream_t stream) {
  const float* x = (const float*)d_in[0];
  const float* qkv_w = (const float*)d_in[1];
  const float* qkv_b = (const float*)d_in[2];
  const float* proj_w = (const float*)d_in[3];
  const float* proj_b = (const float*)d_in[4];
  float* out = (float*)d_out;

  float* ws = (float*)d_ws;
  float* t_mean = ws;                                       // 65536
  float* q0k0_part = ws + 65536;                            // 524288
  float* S = ws + 589824;                                   // 131584
  float* attn = ws + 721408;                                // 131584
  float* u = ws + 852992;                                   // 524288
  float* out0_part = ws + 1377280;                          // 262144
  float* out_part = ws + 1639424;                           // 262144
  float2* sc = (float2*)(ws + 1901568);                     // 16384 float2
  unsigned short* wk_bf = (unsigned short*)(ws + 1934336);  // 1M u16
  unsigned short* x_t = (unsigned short*)(ws + 2458624);    // 16.78M u16

  // 1. fused prep: transpose+mean | wk->bf16 | sc table
  prep_kernel<<<2112, 256, 0, stream>>>(x, qkv_w, x_t, t_mean, wk_bf, sc);

  // 2. q0k0 partials: t_mean @ qkv_w[0:2048].T  (M=64,N=2048,K=4x256)
  gemm_splitk<<<dim3(32, 2, 4), 256, 0, stream>>>(t_mean, 1024, 0, qkv_w, 1024, 0,
                                                  q0k0_part, 2048, 0, 131072, 4);

  // 3. fused K-GEMM + RoPE + scores (double-buffered MFMA)
  k_scores_mfma<<<1024, 512, 0, stream>>>(wk_bf, x_t, qkv_b, q0k0_part, sc, S);

  // 4. token-0 score + softmax
  softmax_kernel<<<512, 64, 0, stream>>>(q0k0_part, qkv_b, S, attn);

  // 5. u = attn^T * t (bf16 x_t)
  u_accum_kernel<<<dim3(8, 64), 256, 0, stream>>>(x_t, t_mean, attn, u);

  // 6. out0 partials: per-head Wv_h . u  (Z=8, K=4x256)
  gemm_splitk<<<dim3(2, 2, 32), 256, 0, stream>>>(u, 8192, 1024,
                                                  qkv_w + (size_t)2048 * 1024, 1024, 131072,
                                                  out0_part, 1024, 128, 65536, 4);

  // 7. proj partials, A = reduce4(out0_part)+bias_v inline
  gemm_proj_splitk<<<dim3(16, 2, 4), 256, 0, stream>>>(out0_part, qkv_b + 2048, proj_w, out_part);

  // 8. final reduce + proj bias
  reduce4_bias<<<256, 256, 0, stream>>>(out_part, proj_b, out);
}

// Round 5
// 110.075 us; speedup vs baseline: 6.2987x; 1.0360x over previous
//
#include <hip/hip_runtime.h>
#include <math.h>

#define PI_F 3.14159265358979323846f
#define KSTEP 0.21959209425992272f /* (log2(224)-1)/31 */

using bf16x8 = __attribute__((ext_vector_type(8))) short;
using f32x4 = __attribute__((ext_vector_type(4))) float;
using u16x8 = __attribute__((ext_vector_type(8))) unsigned short;

static __device__ __forceinline__ float wave_reduce_sum(float v) {
#pragma unroll
  for (int off = 32; off; off >>= 1) v += __shfl_down(v, off);
  return v;
}

static __device__ __forceinline__ unsigned short f2bf(float f) {
  unsigned u = __float_as_uint(f);
  return (unsigned short)((u + 0x7fffu + ((u >> 16) & 1u)) >> 16);
}

static __device__ __forceinline__ float bf2f(unsigned short s) {
  return __uint_as_float(((unsigned)s) << 16);
}

static __device__ __forceinline__ void gload_lds16(const void* g, void* l) {
  __builtin_amdgcn_global_load_lds((const __attribute__((address_space(1))) unsigned int*)g,
                                   (__attribute__((address_space(3))) unsigned int*)l, 16, 0, 0);
}

// ---------------- fused prep: transpose x->bf16 x_t + t_mean | Wk->bf16 | sc table ----------------
__global__ __launch_bounds__(256) void prep_kernel(const float* __restrict__ x,
                                                   const float* __restrict__ qkv_w,
                                                   unsigned short* __restrict__ xt,
                                                   float* __restrict__ t_mean,
                                                   unsigned short* __restrict__ wk_bf,
                                                   float2* __restrict__ sc) {
  const int bid = blockIdx.x;
  const int t = threadIdx.x;
  __shared__ float tile[64][33];
  if (bid < 1024) {
    const int ct = bid & 15, b = bid >> 4;
    const int cl = t >> 2, pq = (t & 3) * 8;  // read role
    const int pl = t >> 3, cq = (t & 7) * 8;  // write role
    float sum = 0.0f;
    const float* xrow = x + ((size_t)(b * 1024 + ct * 64 + cl) * 256) + pq;
    unsigned short* xtb = xt + (size_t)b * 262144 + ct * 64;
    for (int pt = 0; pt < 8; ++pt) {
      const float4 v0 = *reinterpret_cast<const float4*>(xrow + pt * 32);
      const float4 v1 = *reinterpret_cast<const float4*>(xrow + pt * 32 + 4);
      tile[cl][pq + 0] = v0.x; tile[cl][pq + 1] = v0.y; tile[cl][pq + 2] = v0.z; tile[cl][pq + 3] = v0.w;
      tile[cl][pq + 4] = v1.x; tile[cl][pq + 5] = v1.y; tile[cl][pq + 6] = v1.z; tile[cl][pq + 7] = v1.w;
      sum += (v0.x + v0.y) + (v0.z + v0.w) + (v1.x + v1.y) + (v1.z + v1.w);
      __syncthreads();
      u16x8 o;
#pragma unroll
      for (int e = 0; e < 8; ++e) o[e] = f2bf(tile[cq + e][pl]);
      *reinterpret_cast<u16x8*>(xtb + (size_t)(pt * 32 + pl) * 1024 + cq) = o;
      __syncthreads();
    }
    sum += __shfl_xor(sum, 1);
    sum += __shfl_xor(sum, 2);
    if ((t & 3) == 0) t_mean[b * 1024 + ct * 64 + cl] = sum * (1.0f / 256.0f);
  } else if (bid < 2048) {
    const int i = ((bid - 1024) * 256 + t) * 4;
    const float4 v = *reinterpret_cast<const float4*>(qkv_w + 1048576 + i);
    ushort4 r;
    r.x = f2bf(v.x); r.y = f2bf(v.y); r.z = f2bf(v.z); r.w = f2bf(v.w);
    *reinterpret_cast<ushort4*>(wk_bf + i) = r;
  } else {
    const int idx = (bid - 2048) * 256 + t;  // 16384
    const int m = idx >> 8, j = idx & 255;
    const float band = exp2f((float)(m & 31) * KSTEP) * PI_F;
    const float coord = (m < 32) ? (-1.0f + (2.0f / 15.0f) * (float)(j >> 4))
                                 : (-1.0f + (2.0f / 15.0f) * (float)(j & 15));
    float sn, cs;
    sincosf(coord * band, &sn, &cs);
    sc[idx] = make_float2(sn, cs);
  }
}

// ---------------- split-K skinny GEMM: Cp[kc] = A * B^T (K-chunk = 256) ----------------
__global__ __launch_bounds__(256) void gemm_splitk(
    const float* __restrict__ A, int lda, int aStrideZ,
    const float* __restrict__ B, int ldb, int bStrideZ,
    float* __restrict__ Cp, int ldc, int cStrideZ, int cStrideKc, int KC) {
  const int nt = blockIdx.x, mt = blockIdx.y;
  const int z = blockIdx.z / KC, kc = blockIdx.z % KC;
  const int tid = threadIdx.x;
  A += (size_t)z * aStrideZ + (size_t)mt * 32 * lda + kc * 256;
  B += (size_t)z * bStrideZ + (size_t)nt * 64 * ldb + kc * 256;
  Cp += (size_t)kc * cStrideKc + (size_t)z * cStrideZ + (size_t)mt * 32 * ldc + nt * 64;

  __shared__ float As[32][34];
  __shared__ float Bs[32][68];

  const int tm = tid >> 4;
  const int tn = tid & 15;
  float acc0[4] = {0, 0, 0, 0}, acc1[4] = {0, 0, 0, 0};

  for (int k0 = 0; k0 < 256; k0 += 32) {
    {
      const int m = tid >> 3, kq = tid & 7;
      float4 v = *reinterpret_cast<const float4*>(A + (size_t)m * lda + k0 + kq * 4);
      As[kq * 4 + 0][m] = v.x; As[kq * 4 + 1][m] = v.y;
      As[kq * 4 + 2][m] = v.z; As[kq * 4 + 3][m] = v.w;
    }
#pragma unroll
    for (int r = 0; r < 2; ++r) {
      const int idx = r * 256 + tid;
      const int n = idx >> 3, kq = idx & 7;
      float4 v = *reinterpret_cast<const float4*>(B + (size_t)n * ldb + k0 + kq * 4);
      Bs[kq * 4 + 0][n] = v.x; Bs[kq * 4 + 1][n] = v.y;
      Bs[kq * 4 + 2][n] = v.z; Bs[kq * 4 + 3][n] = v.w;
    }
    __syncthreads();
#pragma unroll
    for (int k = 0; k < 32; ++k) {
      const float a0 = As[k][tm * 2], a1 = As[k][tm * 2 + 1];
      const float4 bb = *reinterpret_cast<const float4*>(&Bs[k][tn * 4]);
      acc0[0] += a0 * bb.x; acc0[1] += a0 * bb.y; acc0[2] += a0 * bb.z; acc0[3] += a0 * bb.w;
      acc1[0] += a1 * bb.x; acc1[1] += a1 * bb.y; acc1[2] += a1 * bb.z; acc1[3] += a1 * bb.w;
    }
    __syncthreads();
  }
  *reinterpret_cast<float4*>(Cp + (size_t)(tm * 2) * ldc + tn * 4) =
      make_float4(acc0[0], acc0[1], acc0[2], acc0[3]);
  *reinterpret_cast<float4*>(Cp + (size_t)(tm * 2 + 1) * ldc + tn * 4) =
      make_float4(acc1[0], acc1[1], acc1[2], acc1[3]);
}

// ---------------- proj GEMM with inline 4-partial A reduce + Wv-bias ----------------
__global__ __launch_bounds__(256) void gemm_proj_splitk(
    const float* __restrict__ Apart, const float* __restrict__ abias,
    const float* __restrict__ B, float* __restrict__ Cp) {
  const int nt = blockIdx.x, mt = blockIdx.y, kc = blockIdx.z;
  const int tid = threadIdx.x;
  B += (size_t)nt * 64 * 1024 + kc * 256;
  Cp += (size_t)kc * 65536 + (size_t)mt * 32 * 1024 + nt * 64;

  __shared__ float As[32][34];
  __shared__ float Bs[32][68];

  const int tm = tid >> 4;
  const int tn = tid & 15;
  float acc0[4] = {0, 0, 0, 0}, acc1[4] = {0, 0, 0, 0};

  for (int k0 = 0; k0 < 256; k0 += 32) {
    {
      const int m = tid >> 3, kq = tid & 7;
      const int kg = kc * 256 + k0 + kq * 4;
      const float* Ab = Apart + (size_t)(mt * 32 + m) * 1024 + kg;
      float4 v = *reinterpret_cast<const float4*>(abias + kg);
#pragma unroll
      for (int r = 0; r < 4; ++r) {
        const float4 p = *reinterpret_cast<const float4*>(Ab + (size_t)r * 65536);
        v.x += p.x; v.y += p.y; v.z += p.z; v.w += p.w;
      }
      As[kq * 4 + 0][m] = v.x; As[kq * 4 + 1][m] = v.y;
      As[kq * 4 + 2][m] = v.z; As[kq * 4 + 3][m] = v.w;
    }
#pragma unroll
    for (int r = 0; r < 2; ++r) {
      const int idx = r * 256 + tid;
      const int n = idx >> 3, kq = idx & 7;
      float4 v = *reinterpret_cast<const float4*>(B + (size_t)n * 1024 + k0 + kq * 4);
      Bs[kq * 4 + 0][n] = v.x; Bs[kq * 4 + 1][n] = v.y;
      Bs[kq * 4 + 2][n] = v.z; Bs[kq * 4 + 3][n] = v.w;
    }
    __syncthreads();
#pragma unroll
    for (int k = 0; k < 32; ++k) {
      const float a0 = As[k][tm * 2], a1 = As[k][tm * 2 + 1];
      const float4 bb = *reinterpret_cast<const float4*>(&Bs[k][tn * 4]);
      acc0[0] += a0 * bb.x; acc0[1] += a0 * bb.y; acc0[2] += a0 * bb.z; acc0[3] += a0 * bb.w;
      acc1[0] += a1 * bb.x; acc1[1] += a1 * bb.y; acc1[2] += a1 * bb.z; acc1[3] += a1 * bb.w;
    }
    __syncthreads();
  }
  *reinterpret_cast<float4*>(Cp + (size_t)(tm * 2) * 1024 + tn * 4) =
      make_float4(acc0[0], acc0[1], acc0[2], acc0[3]);
  *reinterpret_cast<float4*>(Cp + (size_t)(tm * 2 + 1) * 1024 + tn * 4) =
      make_float4(acc1[0], acc1[1], acc1[2], acc1[3]);
}

// ---------------- reduce 4 split-K partials + bias ----------------
__global__ __launch_bounds__(256) void reduce4_bias(const float* __restrict__ part,
                                                    const float* __restrict__ bias,
                                                    float* __restrict__ out) {
  const int i = blockIdx.x * 256 + threadIdx.x;  // 65536
  out[i] = part[i] + part[i + 65536] + part[i + 131072] + part[i + 196608] + bias[i & 1023];
}

// ---------------- MFMA K-GEMM + RoPE-dot + fused softmax ----------------
// Block (b, mt): rows mt*256..+256 of K_all (2 heads) x all 256 j, K=1024.
// Deep pipeline: BK=32, 4 LDS buffers (128 KB), stage distance 3,
// counted s_waitcnt vmcnt(12) + raw s_barrier (never drains in-loop).
// Epilogue: q0/k0 partial-reduce, RoPE-rotated dot, per-head softmax -> attn.
__global__ __launch_bounds__(512, 1) void k_scores_mfma(
    const unsigned short* __restrict__ wk, const unsigned short* __restrict__ xt,
    const float* __restrict__ qkv_b, const float* __restrict__ q0p,
    const float2* __restrict__ sc, float* __restrict__ attn) {
  const int l = blockIdx.x;  // 256; same-b blocks share an XCD (l&7 preserved)
  const int b = ((l >> 5) << 3) | (l & 7);
  const int mt = (l >> 3) & 3;
  const int tid = threadIdx.x;
  const int w = tid >> 6, lane = tid & 63;
  const int wr = w >> 2, wc = w & 3;  // wave tile: 128d x 64j

  __shared__ __align__(16) char smem[131072];  // 4 bufs x (A 16KB + B 16KB)

  const unsigned short* wkA = wk + (size_t)(mt * 256) * 1024;
  const unsigned short* xtb = xt + (size_t)b * 262144;

  f32x4 acc[8][4] = {};

  // Stage one BK=32 tile (A rows 256, B rows 256) into buffer tt&3.
  // Source c-slot pre-swizzled so linear LDS + swizzled ds_read match (rule 21).
#define STAGE4(tt, src)                                                          \
  {                                                                              \
    char* base_ = smem + ((tt)&3) * 32768;                                       \
    const int c0_ = (src)*32;                                                    \
    _Pragma("unroll") for (int c = 0; c < 2; ++c) {                              \
      const int rb_ = w * 2 + c;                                                 \
      const int row_ = rb_ * 16 + (lane >> 2);                                   \
      const int sl_ = ((lane & 3) ^ ((row_ >> 1) & 3)) * 8;                      \
      gload_lds16(wkA + (size_t)row_ * 1024 + c0_ + sl_, base_ + rb_ * 1024);    \
      gload_lds16(xtb + (size_t)row_ * 1024 + c0_ + sl_,                         \
                  base_ + 16384 + rb_ * 1024);                                   \
    }                                                                            \
  }

  STAGE4(0, 0);
  STAGE4(1, 1);
  STAGE4(2, 2);

  for (int t = 0; t < 32; ++t) {
    {  // stage t+3 (clamped source keeps vmcnt timeline uniform; stray writes
       // land in already-consumed buffers)
      const int tt = t + 3;
      const int src = tt > 31 ? 31 : tt;
      STAGE4(tt, src);
    }
    asm volatile("s_waitcnt vmcnt(12)" ::: "memory");  // tile t resident (per-wave), 3 tiles in flight
    __builtin_amdgcn_s_barrier();                      // all waves' shares of tile t done
    const char* Ab = smem + (t & 3) * 32768;
    const char* Bb = Ab + 16384;
    bf16x8 bfrag[4];
#pragma unroll
    for (int ni = 0; ni < 4; ++ni) {
      const int row = wc * 64 + ni * 16 + (lane & 15);
      bfrag[ni] = *reinterpret_cast<const bf16x8*>(
          Bb + row * 64 + (((lane >> 4) ^ ((row >> 1) & 3)) << 4));
    }
#pragma unroll
    for (int mh = 0; mh < 2; ++mh) {
      bf16x8 af[4];
#pragma unroll
      for (int q = 0; q < 4; ++q) {
        const int row = wr * 128 + (mh * 4 + q) * 16 + (lane & 15);
        af[q] = *reinterpret_cast<const bf16x8*>(
            Ab + row * 64 + (((lane >> 4) ^ ((row >> 1) & 3)) << 4));
      }
      __builtin_amdgcn_s_setprio(1);
#pragma unroll
      for (int q = 0; q < 4; ++q)
#pragma unroll
        for (int ni = 0; ni < 4; ++ni)
          acc[mh * 4 + q][ni] = __builtin_amdgcn_mfma_f32_16x16x32_bf16(
              af[q], bfrag[ni], acc[mh * 4 + q][ni], 0, 0, 0);
      __builtin_amdgcn_s_setprio(0);
    }
    __builtin_amdgcn_s_barrier();  // readers done before next iter overwrites buf[t&3]
    asm volatile("" ::: "memory"); // keep next STAGE below the barrier
  }
#undef STAGE4

  asm volatile("s_waitcnt vmcnt(0)" ::: "memory");  // drain stray stages before LDS reuse
  __syncthreads();

  // LDS reuse for epilogue
  float* q0_lds = reinterpret_cast<float*>(smem);  // [256] q for this block's 2 heads
  float* k0_lds = q0_lds + 256;                    // [256]
  float* Sh = k0_lds + 256;                        // [2][260]: [h][0]=tok0, [h][1+j]
  float* ps = Sh + 520;                            // [4] token-0 partials
  float* r4 = ps + 4;                              // [2][4] softmax reduce

  if (tid < 256) {
    const float* qp = q0p + (size_t)b * 2048 + mt * 256 + tid;
    q0_lds[tid] = qkv_b[mt * 256 + tid] + qp[0] + qp[131072] + qp[262144] + qp[393216];
    const float* kp = qp + 1024;
    k0_lds[tid] = qkv_b[1024 + mt * 256 + tid] + kp[0] + kp[131072] + kp[262144] + kp[393216];
  }
  __syncthreads();

  // token-0 scores (waves 0-3: 64 dims each, head = tid>>7)
  if (tid < 256) {
    float pr = q0_lds[tid] * k0_lds[tid];
    pr = wave_reduce_sum(pr);
    if (lane == 0) ps[tid >> 6] = pr;
  }

  // RoPE-rotated dot over this lane's acc rows
  const int colj = lane & 15, rgrp = lane >> 4;
  const float* bk = qkv_b + 1024 + mt * 256 + wr * 128;
  float partial[4] = {0, 0, 0, 0};
#pragma unroll
  for (int mi = 0; mi < 8; ++mi) {
#pragma unroll
    for (int pp = 0; pp < 2; ++pp) {
      const int dd = mi * 16 + rgrp * 4 + pp * 2;  // dim within head
      const int m = dd >> 1;
      const float2 qv = *reinterpret_cast<const float2*>(q0_lds + wr * 128 + dd);
      const float2 bv = *reinterpret_cast<const float2*>(bk + dd);
#pragma unroll
      for (int ni = 0; ni < 4; ++ni) {
        const int j = wc * 64 + ni * 16 + colj;
        const float ke = acc[mi][ni][pp * 2] + bv.x;
        const float ko = acc[mi][ni][pp * 2 + 1] + bv.y;
        const float2 tt = sc[m * 256 + j];
        partial[ni] += tt.y * (ke * qv.x + ko * qv.y) + tt.x * (ke * qv.y - ko * qv.x);
      }
    }
  }
#pragma unroll
  for (int ni = 0; ni < 4; ++ni) {
    partial[ni] += __shfl_xor(partial[ni], 16);
    partial[ni] += __shfl_xor(partial[ni], 32);
  }
  if (lane < 16) {
#pragma unroll
    for (int ni = 0; ni < 4; ++ni)
      Sh[wr * 260 + 1 + wc * 64 + ni * 16 + colj] = partial[ni];
  }
  __syncthreads();
  if (tid == 0) { Sh[0] = ps[0] + ps[1]; Sh[260] = ps[2] + ps[3]; }
  __syncthreads();

  // fused softmax: two 256-thread groups, one head each (257 tokens)
  const int hg = tid >> 8, i = tid & 255;
  const float scale = 0.08838834764831845f;
  const float* Sr = Sh + hg * 260;
  const float va = Sr[i] * scale;
  const float vb = (i == 0) ? Sr[256] * scale : -3.0e38f;
  float mx = fmaxf(va, vb);
#pragma unroll
  for (int off = 32; off; off >>= 1) mx = fmaxf(mx, __shfl_xor(mx, off));
  if (lane == 0) r4[hg * 4 + ((tid >> 6) & 3)] = mx;
  __syncthreads();
  mx = fmaxf(fmaxf(r4[hg * 4], r4[hg * 4 + 1]), fmaxf(r4[hg * 4 + 2], r4[hg * 4 + 3]));
  const float ea = expf(va - mx);
  const float eb = (i == 0) ? expf(vb - mx) : 0.0f;
  float sum = ea + eb;
#pragma unroll
  for (int off = 32; off; off >>= 1) sum += __shfl_xor(sum, off);
  __syncthreads();
  if (lane == 0) r4[hg * 4 + ((tid >> 6) & 3)] = sum;
  __syncthreads();
  sum = r4[hg * 4] + r4[hg * 4 + 1] + r4[hg * 4 + 2] + r4[hg * 4 + 3];
  const float inv = 1.0f / sum;
  float* ab = attn + (size_t)(b * 8 + 2 * mt + hg) * 257;
  ab[i] = ea * inv;
  if (i == 0) ab[256] = eb * inv;
}

// ---------------- u[b,h,c] = sum_j attn[b,h,j] * t_j[c]  (reads bf16 x_t) ----------------
__global__ __launch_bounds__(256) void u_accum_kernel(const unsigned short* __restrict__ xt,
                                                      const float* __restrict__ t_mean,
                                                      const float* __restrict__ attn,
                                                      float* __restrict__ u) {
  const int ct = blockIdx.x;  // 8 tiles of 128 channels
  const int b = blockIdx.y;
  const int tid = threadIdx.x;
  __shared__ float aw[2056];
  __shared__ float red[8192];  // [8 q][1024]
  for (int i = tid; i < 2056; i += 256) aw[i] = attn[(size_t)(b * 8 + (i & 7)) * 257 + (i >> 3)];
  __syncthreads();
  const int cl = tid & 31, q = tid >> 5;
  const int c = ct * 128 + cl * 4;
  const unsigned short* xr = xt + (size_t)b * 262144 + c;
  float acc[8][4] = {};
  for (int p = q * 32; p < q * 32 + 32; ++p) {
    const ushort4 v = *reinterpret_cast<const ushort4*>(xr + (size_t)p * 1024);
    const float xs[4] = {bf2f(v.x), bf2f(v.y), bf2f(v.z), bf2f(v.w)};
    const float* w8 = &aw[(p + 1) * 8];
#pragma unroll
    for (int hh = 0; hh < 8; ++hh)
#pragma unroll
      for (int e = 0; e < 4; ++e) acc[hh][e] += w8[hh] * xs[e];
  }
#pragma unroll
  for (int hh = 0; hh < 8; ++hh)
#pragma unroll
    for (int e = 0; e < 4; ++e) red[q * 1024 + (cl * 8 + hh) * 4 + e] = acc[hh][e];
  __syncthreads();
#pragma unroll
  for (int r = 0; r < 4; ++r) {
    const int o = tid * 4 + r;  // 0..1023
    const int cl2 = o >> 5, hh = (o >> 2) & 7, e = o & 3;
    float s = 0.0f;
#pragma unroll
    for (int qq = 0; qq < 8; ++qq) s += red[qq * 1024 + o];
    const int cc = ct * 128 + cl2 * 4 + e;
    s += aw[hh] * t_mean[b * 1024 + cc];
    u[(size_t)(b * 8 + hh) * 1024 + cc] = s;
  }
}

// ---------------- host side ----------------
extern "C" void kernel_launch(void* const* d_in, const int* in_sizes, int n_in,
                              void* d_out, int out_size, void* d_ws, size_t ws_size,
                              hipStream_t stream) {
  const float* x = (const float*)d_in[0];
  const float* qkv_w = (const float*)d_in[1];
  const float* qkv_b = (const float*)d_in[2];
  const float* proj_w = (const float*)d_in[3];
  const float* proj_b = (const float*)d_in[4];
  float* out = (float*)d_out;

  float* ws = (float*)d_ws;
  float* t_mean = ws;                                       // 65536
  float* q0k0_part = ws + 65536;                            // 524288
  float* attn = ws + 721408;                                // 131584
  float* u = ws + 852992;                                   // 524288
  float* out0_part = ws + 1377280;                          // 262144
  float* out_part = ws + 1639424;                           // 262144
  float2* sc = (float2*)(ws + 1901568);                     // 16384 float2
  unsigned short* wk_bf = (unsigned short*)(ws + 1934336);  // 1M u16
  unsigned short* x_t = (unsigned short*)(ws + 2458624);    // 16.78M u16

  // 1. fused prep: transpose+mean | wk->bf16 | sc table
  prep_kernel<<<2112, 256, 0, stream>>>(x, qkv_w, x_t, t_mean, wk_bf, sc);

  // 2. q0k0 partials: t_mean @ qkv_w[0:2048].T  (M=64,N=2048,K=4x256)
  gemm_splitk<<<dim3(32, 2, 4), 256, 0, stream>>>(t_mean, 1024, 0, qkv_w, 1024, 0,
                                                  q0k0_part, 2048, 0, 131072, 4);

  // 3. fused K-GEMM + RoPE + scores + softmax (deep-pipelined MFMA) -> attn
  k_scores_mfma<<<256, 512, 0, stream>>>(wk_bf, x_t, qkv_b, q0k0_part, sc, attn);

  // 4. u = attn^T * t (bf16 x_t)
  u_accum_kernel<<<dim3(8, 64), 256, 0, stream>>>(x_t, t_mean, attn, u);

  // 5. out0 partials: per-head Wv_h . u  (Z=8, K=4x256)
  gemm_splitk<<<dim3(2, 2, 32), 256, 0, stream>>>(u, 8192, 1024,
                                                  qkv_w + (size_t)2048 * 1024, 1024, 131072,
                                                  out0_part, 1024, 128, 65536, 4);

  // 6. proj partials, A = reduce4(out0_part)+bias_v inline
  gemm_proj_splitk<<<dim3(16, 2, 4), 256, 0, stream>>>(out0_part, qkv_b + 2048, proj_w, out_part);

  // 7. final reduce + proj bias
  reduce4_bias<<<256, 256, 0, stream>>>(out_part, proj_b, out);
}